// Round 6
// baseline (1655.179 us; speedup 1.0000x reference)
//
#include <hip/hip_runtime.h>
#include <math.h>

#define NN 100000
#define NPAD 100096
#define NT 782        // NPAD / 128  (memory tiles)
#define NT2 1564      // NPAD / 64   (gemm/gru blocks)
#define NE 800000
#define DD 128

typedef __attribute__((ext_vector_type(8))) short short8;
typedef __attribute__((ext_vector_type(4))) float floatx4;
typedef unsigned int uint_t;
typedef unsigned short ush_t;

__device__ __forceinline__ ush_t f2bf(float f) {
    unsigned u = __float_as_uint(f);
    return (ush_t)((u + 0x7fffu + ((u >> 16) & 1u)) >> 16);
}
__device__ __forceinline__ float bf2f(ush_t h) {
    return __uint_as_float((unsigned)h << 16);
}
__device__ __forceinline__ void split2(float f, ush_t* H, ush_t* L) {
    ush_t h = f2bf(f);
    *H = h;
    *L = f2bf(f - bf2f(h));
}
__device__ __forceinline__ float sigf(float x) {
    return __builtin_amdgcn_rcpf(1.0f + __expf(-x));
}
__device__ __forceinline__ float tanhf_fast(float x) {
    x = fminf(fmaxf(x, -20.0f), 20.0f);
    float e = __expf(2.0f * x);
    return 1.0f - 2.0f * __builtin_amdgcn_rcpf(e + 1.0f);
}

// ---------------------------------------------------------------- row means of edge-type table
__global__ void rowmean_kernel(const float* __restrict__ tab, float* __restrict__ rm) {
    int r = blockIdx.x;
    int t = threadIdx.x;
    float v = tab[r * DD + t];
    #pragma unroll
    for (int o = 32; o > 0; o >>= 1) v += __shfl_xor(v, o);
    __shared__ float red[2];
    if ((t & 63) == 0) red[t >> 6] = v;
    __syncthreads();
    if (t == 0) rm[r] = (red[0] + red[1]) * (1.0f / DD);
}

// ---------------------------------------------------------------- CSR build
__global__ void hist_kernel(const int* __restrict__ dst, int* __restrict__ fill) {
    int e = blockIdx.x * 256 + threadIdx.x;
    if (e < NE) atomicAdd(&fill[dst[e]], 1);
}

__global__ __launch_bounds__(1024) void scan_kernel(const int* __restrict__ cnt,
                                                    int* __restrict__ rp) {
    __shared__ int wsum[16];
    __shared__ int carry_s;
    int t = threadIdx.x;
    int lane = t & 63, w = t >> 6;
    if (t == 0) { carry_s = 0; rp[0] = 0; }
    __syncthreads();
    for (int base = 0; base < NN; base += 1024) {
        int i = base + t;
        int v = (i < NN) ? cnt[i] : 0;
        int sv = v;
        #pragma unroll
        for (int off = 1; off < 64; off <<= 1) {
            int u = __shfl_up(sv, off);
            if (lane >= off) sv += u;
        }
        if (lane == 63) wsum[w] = sv;
        __syncthreads();
        int woff = carry_s;
        for (int j = 0; j < w; ++j) woff += wsum[j];
        if (i < NN) rp[i + 1] = sv + woff;
        __syncthreads();
        if (t == 0) {
            int tot = 0;
            for (int j = 0; j < 16; ++j) tot += wsum[j];
            carry_s += tot;
        }
        __syncthreads();
    }
}

__global__ void place_kernel(const int* __restrict__ src, const int* __restrict__ dst,
                             const int* __restrict__ et, const float* __restrict__ rm,
                             const int* __restrict__ rp, int* __restrict__ fill,
                             int* __restrict__ csr_s, float* __restrict__ csr_w) {
    int e = blockIdx.x * 256 + threadIdx.x;
    if (e < NE) {
        int d = dst[e];
        int pos = rp[d] + atomicAdd(&fill[d], 1);
        csr_s[pos] = src[e];
        csr_w[pos] = rm[et[e] - 1];
    }
}

// ---------------------------------------------------------------- embedding gather → H/L planes
__global__ void embed_kernel(const int* __restrict__ ids, const float* __restrict__ tab,
                             ush_t* __restrict__ xH, ush_t* __restrict__ xL) {
    int tid = blockIdx.x * 256 + threadIdx.x;   // NPAD*16
    int n = tid >> 4, c = tid & 15;
    if (n >= NPAD) return;
    int k = c * 8;
    int base = ((n >> 7) << 14) + ((k >> 5) << 12) + (((n >> 4) & 7) << 9)
             + (((k >> 3) & 3) << 7) + ((n & 15) << 3);
    ushort4 h0, h1, l0, l1;
    if (n < NN) {
        const float4* srcp = (const float4*)(tab + (size_t)(ids[n] + 1) * DD + k);
        float4 v0 = srcp[0], v1 = srcp[1];
        split2(v0.x, &h0.x, &l0.x); split2(v0.y, &h0.y, &l0.y);
        split2(v0.z, &h0.z, &l0.z); split2(v0.w, &h0.w, &l0.w);
        split2(v1.x, &h1.x, &l1.x); split2(v1.y, &h1.y, &l1.y);
        split2(v1.z, &h1.z, &l1.z); split2(v1.w, &h1.w, &l1.w);
    } else {
        h0 = make_ushort4(0, 0, 0, 0); h1 = h0; l0 = h0; l1 = h0;
    }
    *(ushort4*)(xH + base) = h0; *(ushort4*)(xH + base + 4) = h1;
    *(ushort4*)(xL + base) = l0; *(ushort4*)(xL + base + 4) = l1;
}

// ---------------------------------------------------------------- weight prep
// mats 0..2: Whh gates r,z,n | 3..5: Wih gates r,z,n | 6..9: ggnn layer W
__global__ void wprep_kernel(const float* __restrict__ Wih, const float* __restrict__ Whh,
                             const float* __restrict__ G, ush_t* __restrict__ WB) {
    int idx = blockIdx.x * 256 + threadIdx.x;   // 10*16384
    int mat = idx >> 14;
    int rem = idx & 16383;
    int col = rem & 127, kk = rem >> 7;
    float w;
    if (mat < 3)      w = Whh[((size_t)mat * 128 + col) * 128 + kk];
    else if (mat < 6) w = Wih[((size_t)(mat - 3) * 128 + col) * 128 + kk];
    else              w = G[(size_t)(mat - 6) * 16384 + (size_t)kk * 128 + col];
    int chunk = kk >> 5, klo = kk & 31;
    int inoff = ((col >> 4) * 4 + (klo >> 3)) * 128 + (col & 15) * 8 + (klo & 7);
    ush_t h, l;
    split2(w, &h, &l);
    size_t base = (size_t)((mat * 4 + chunk) * 2) * 4096;
    WB[base + inoff] = h;
    WB[base + 4096 + inoff] = l;
}

// ---------------------------------------------------------------- m = x @ W  (zero-LDS MFMA)
// reads x H/L planes (frag order), writes ROW-MAJOR single-plane bf16 m
__global__ __launch_bounds__(256, 4) void gemm_mfma_kernel(const ush_t* __restrict__ xH,
                                                           const ush_t* __restrict__ xL,
                                                           const ush_t* __restrict__ WB,
                                                           int mat, ush_t* __restrict__ mRM) {
    int t = threadIdx.x;
    int tb = blockIdx.x;                 // 64-row tile
    int l = t & 63, w = t >> 6;          // w = colgrp 0..3
    int lg = l >> 4, lc = l & 15;
    floatx4 acc[4][2];
    #pragma unroll
    for (int i = 0; i < 4; ++i)
        #pragma unroll
        for (int j = 0; j < 2; ++j) acc[i][j] = (floatx4)0.f;
    int abase = (tb >> 1) * 16384 + (tb & 1) * 2048 + lg * 128 + lc * 8;
    #pragma unroll
    for (int kc = 0; kc < 4; ++kc) {
        short8 aH[4], aL[4];
        #pragma unroll
        for (int i = 0; i < 4; ++i) {
            int off = abase + kc * 4096 + i * 512;
            aH[i] = *(const short8*)(xH + off);
            aL[i] = *(const short8*)(xL + off);
        }
        #pragma unroll
        for (int j = 0; j < 2; ++j) {
            int boff = (((w * 2 + j) * 4 + lg) * 16 + lc) * 8;
            const ush_t* wb = WB + (size_t)((mat * 4 + kc) * 2) * 4096;
            short8 bH = *(const short8*)(wb + boff);
            short8 bL = *(const short8*)(wb + 4096 + boff);
            #pragma unroll
            for (int i = 0; i < 4; ++i) {
                acc[i][j] = __builtin_amdgcn_mfma_f32_16x16x32_bf16(aH[i], bH, acc[i][j], 0, 0, 0);
                acc[i][j] = __builtin_amdgcn_mfma_f32_16x16x32_bf16(aH[i], bL, acc[i][j], 0, 0, 0);
                acc[i][j] = __builtin_amdgcn_mfma_f32_16x16x32_bf16(aL[i], bH, acc[i][j], 0, 0, 0);
            }
        }
    }
    #pragma unroll
    for (int j = 0; j < 2; ++j) {
        int col = w * 32 + j * 16 + lc;
        #pragma unroll
        for (int i = 0; i < 4; ++i)
            #pragma unroll
            for (int r = 0; r < 4; ++r) {
                int row = tb * 64 + i * 16 + lg * 4 + r;
                mRM[(size_t)row * DD + col] = f2bf(acc[i][j][r]);
            }
    }
}

// ---------------------------------------------------------------- CSR aggregation
// reads bf16 row-major m (256 B/edge), writes agg H/L planes (frag order)
__global__ __launch_bounds__(256) void agg_kernel(const ush_t* __restrict__ m,
                                                  const int* __restrict__ rp,
                                                  const int* __restrict__ csr_s,
                                                  const float* __restrict__ csr_w,
                                                  ush_t* __restrict__ aggH,
                                                  ush_t* __restrict__ aggL) {
    int t = threadIdx.x;
    int grp = t >> 5, c = t & 31;
    int n = blockIdx.x * 8 + grp;
    if (n >= NPAD) return;
    int nout = ((n >> 7) << 14) + ((c >> 3) << 12) + (((n >> 4) & 7) << 9)
             + (((c >> 1) & 3) << 7) + ((n & 15) << 3) + ((c & 1) << 2);
    ushort4 zh = make_ushort4(0, 0, 0, 0);
    if (n >= NN) {
        *(ushort4*)(aggH + nout) = zh;
        *(ushort4*)(aggL + nout) = zh;
        return;
    }
    int e0 = rp[n], e1 = rp[n + 1];
    float4 acc = make_float4(0.f, 0.f, 0.f, 0.f);
    for (int e = e0; e < e1; ++e) {
        float w0 = csr_w[e];
        int s0 = csr_s[e];
        ushort4 p = *(const ushort4*)(m + (size_t)s0 * DD + c * 4);
        acc.x += w0 * bf2f(p.x);
        acc.y += w0 * bf2f(p.y);
        acc.z += w0 * bf2f(p.z);
        acc.w += w0 * bf2f(p.w);
    }
    ushort4 oh, ol;
    split2(acc.x, &oh.x, &ol.x); split2(acc.y, &oh.y, &ol.y);
    split2(acc.z, &oh.z, &ol.z); split2(acc.w, &oh.w, &ol.w);
    *(ushort4*)(aggH + nout) = oh;
    *(ushort4*)(aggL + nout) = ol;
}

// ---------------------------------------------------------------- fused GRU (zero-LDS MFMA)
// pass 0: A = x vs Whh (mats 0..2) → accR,accZ,accN ; pass 1: A = agg vs Wih (3..5) → accR,accZ,accI
__global__ __launch_bounds__(256, 4) void gru_mfma_kernel(const ush_t* __restrict__ aggH,
                                                          const ush_t* __restrict__ aggL,
                                                          const ush_t* __restrict__ xH,
                                                          const ush_t* __restrict__ xL,
                                                          const ush_t* __restrict__ WB,
                                                          const float* __restrict__ bih,
                                                          const float* __restrict__ bhh,
                                                          ush_t* __restrict__ xoH,
                                                          ush_t* __restrict__ xoL) {
    int t = threadIdx.x;
    int tb = blockIdx.x;                 // 64-row tile
    int l = t & 63, w = t >> 6;          // w = colgrp
    int lg = l >> 4, lc = l & 15;
    floatx4 accR[4][2], accZ[4][2], accN[4][2], accI[4][2];
    #pragma unroll
    for (int i = 0; i < 4; ++i)
        #pragma unroll
        for (int j = 0; j < 2; ++j) {
            accR[i][j] = (floatx4)0.f; accZ[i][j] = (floatx4)0.f;
            accN[i][j] = (floatx4)0.f; accI[i][j] = (floatx4)0.f;
        }
    int abase = (tb >> 1) * 16384 + (tb & 1) * 2048 + lg * 128 + lc * 8;
    #pragma unroll
    for (int pass = 0; pass < 2; ++pass) {
        const ush_t* ApH = pass ? aggH : xH;
        const ush_t* ApL = pass ? aggL : xL;
        int matbase = pass ? 3 : 0;
        #pragma unroll
        for (int kc = 0; kc < 4; ++kc) {
            short8 aHf[4], aLf[4];
            #pragma unroll
            for (int i = 0; i < 4; ++i) {
                int off = abase + kc * 4096 + i * 512;
                aHf[i] = *(const short8*)(ApH + off);
                aLf[i] = *(const short8*)(ApL + off);
            }
            #pragma unroll
            for (int m3 = 0; m3 < 3; ++m3) {
                floatx4 (*accp)[2] = (m3 == 0) ? accR : (m3 == 1) ? accZ : (pass ? accI : accN);
                const ush_t* wb = WB + (size_t)(((matbase + m3) * 4 + kc) * 2) * 4096;
                #pragma unroll
                for (int j = 0; j < 2; ++j) {
                    int boff = (((w * 2 + j) * 4 + lg) * 16 + lc) * 8;
                    short8 bH = *(const short8*)(wb + boff);
                    short8 bL = *(const short8*)(wb + 4096 + boff);
                    #pragma unroll
                    for (int i = 0; i < 4; ++i) {
                        accp[i][j] = __builtin_amdgcn_mfma_f32_16x16x32_bf16(aHf[i], bH, accp[i][j], 0, 0, 0);
                        accp[i][j] = __builtin_amdgcn_mfma_f32_16x16x32_bf16(aHf[i], bL, accp[i][j], 0, 0, 0);
                        accp[i][j] = __builtin_amdgcn_mfma_f32_16x16x32_bf16(aLf[i], bH, accp[i][j], 0, 0, 0);
                    }
                }
            }
        }
    }
    // epilogue: gates + blend (fast transcendentals), h from x planes, write xo planes
    #pragma unroll
    for (int j = 0; j < 2; ++j) {
        int col = w * 32 + j * 16 + lc;
        float bIr = bih[col],       bHr = bhh[col];
        float bIz = bih[128 + col], bHz = bhh[128 + col];
        float bIn = bih[256 + col], bHn = bhh[256 + col];
        int cpart = w * 4096 + (j * 2 + (lc >> 3)) * 128 + (lc & 7);
        #pragma unroll
        for (int i = 0; i < 4; ++i)
            #pragma unroll
            for (int r = 0; r < 4; ++r) {
                int row = tb * 64 + i * 16 + lg * 4 + r;
                if (row < NN) {
                    int idx = (tb >> 1) * 16384 + ((tb & 1) * 4 + i) * 512
                            + (lg * 4 + r) * 8 + cpart;
                    float rr = sigf(accR[i][j][r] + bIr + bHr);
                    float zz = sigf(accZ[i][j][r] + bIz + bHz);
                    float nn = tanhf_fast(accI[i][j][r] + bIn + rr * (accN[i][j][r] + bHn));
                    float h = bf2f(xH[idx]) + bf2f(xL[idx]);
                    float v = (1.0f - zz) * nn + zz * h;
                    ush_t oH, oL;
                    split2(v, &oH, &oL);
                    xoH[idx] = oH;
                    xoL[idx] = oL;
                }
            }
    }
}

// ---------------------------------------------------------------- fused pooling (tile-based, planes)
__global__ __launch_bounds__(256) void pool_kernel(const ush_t* __restrict__ xH,
                                                   const ush_t* __restrict__ xL,
                                                   const float* __restrict__ gw,
                                                   const float* __restrict__ gb,
                                                   float* __restrict__ accum,
                                                   float* __restrict__ den) {
    __shared__ float sgw[128];
    __shared__ float rowsum[128];
    __shared__ float pl[128];
    __shared__ float acc2[128];
    int t = threadIdx.x;
    int tb = blockIdx.x;                 // 128-row memory tile
    if (t < 128) { sgw[t] = gw[t]; rowsum[t] = 0.f; acc2[t] = 0.f; }
    __syncthreads();
    const ush_t* xh = xH + (size_t)tb * 16384;
    const ush_t* xl = xL + (size_t)tb * 16384;
    int kc = t >> 6, rg = (t >> 3) & 7, cb = (t >> 1) & 3, rlh = t & 1;
    int colb = kc * 32 + cb * 8;
    float fv[8][8];
    float g[8];
    #pragma unroll
    for (int e = 0; e < 8; ++e) g[e] = sgw[colb + e];
    #pragma unroll
    for (int jh = 0; jh < 8; ++jh) {
        int base = t * 64 + jh * 8;
        short8 a = *(const short8*)(xh + base);
        short8 b = *(const short8*)(xl + base);
        float s = 0.f;
        #pragma unroll
        for (int e = 0; e < 8; ++e) {
            float f = bf2f((ush_t)a[e]) + bf2f((ush_t)b[e]);
            fv[jh][e] = f;
            s += f * g[e];
        }
        atomicAdd(&rowsum[rg * 16 + rlh * 8 + jh], s);
    }
    __syncthreads();
    if (t < 128) {
        int row = tb * 128 + t;
        float pv = 0.f;
        if (row < NN) pv = __expf(sigf(rowsum[t] + gb[0]));
        pl[t] = pv;
    }
    __syncthreads();
    float ws[8];
    #pragma unroll
    for (int e = 0; e < 8; ++e) ws[e] = 0.f;
    #pragma unroll
    for (int jh = 0; jh < 8; ++jh) {
        float pv = pl[rg * 16 + rlh * 8 + jh];
        #pragma unroll
        for (int e = 0; e < 8; ++e) ws[e] += pv * fv[jh][e];
    }
    #pragma unroll
    for (int e = 0; e < 8; ++e) atomicAdd(&acc2[colb + e], ws[e]);
    __syncthreads();
    if (t < 128) atomicAdd(&accum[t], acc2[t]);
    if (t < 64) {
        float v = pl[t] + pl[t + 64];
        #pragma unroll
        for (int o = 32; o > 0; o >>= 1) v += __shfl_xor(v, o);
        if (t == 0) atomicAdd(den, v);
    }
}

__global__ void finalize_kernel(const float* __restrict__ accum, const float* __restrict__ den,
                                float* __restrict__ out) {
    out[threadIdx.x] = accum[threadIdx.x] / den[0];
}

// ---------------------------------------------------------------- launch
extern "C" void kernel_launch(void* const* d_in, const int* in_sizes, int n_in,
                              void* d_out, int out_size, void* d_ws, size_t ws_size,
                              hipStream_t stream) {
    const int*   node_ids    = (const int*)d_in[0];
    const int*   edges       = (const int*)d_in[1];
    const int*   edge_types  = (const int*)d_in[2];
    const float* embed_table = (const float*)d_in[3];
    const float* edge_tab    = (const float*)d_in[4];
    const float* ggnn_w      = (const float*)d_in[5];
    const float* Wih         = (const float*)d_in[6];
    const float* Whh         = (const float*)d_in[7];
    const float* bih         = (const float*)d_in[8];
    const float* bhh         = (const float*)d_in[9];
    const float* gate_w      = (const float*)d_in[10];
    const float* gate_b      = (const float*)d_in[11];
    float* out = (float*)d_out;

    const size_t PL = (size_t)NPAD * DD;       // plane elems
    ush_t* wsb  = (ush_t*)d_ws;
    ush_t* xH   = wsb;             ush_t* xL   = xH + PL;
    ush_t* x2H  = xL + PL;         ush_t* x2L  = x2H + PL;
    ush_t* agH  = x2L + PL;        ush_t* agL  = agH + PL;
    ush_t* mRM  = agL + PL;        // single plane, row-major
    ush_t* WB   = mRM + PL;        // 10*4*2*4096
    float* csr_w = (float*)(WB + 10 * 4 * 2 * 4096);
    float* accum = csr_w + NE;     // 128
    float* den   = accum + DD;     // 1
    float* rm    = den + 1;        // 7(+1)
    int*   rp    = (int*)(rm + 8); // N+1
    int*   fill  = rp + NN + 1;    // N
    int*   csr_s = fill + NN;      // E

    const int* src = edges;
    const int* dst = edges + NE;

    // one-time prep
    rowmean_kernel<<<7, 128, 0, stream>>>(edge_tab, rm);
    hipMemsetAsync(fill, 0, NN * sizeof(int), stream);
    hist_kernel<<<(NE + 255) / 256, 256, 0, stream>>>(dst, fill);
    scan_kernel<<<1, 1024, 0, stream>>>(fill, rp);
    hipMemsetAsync(fill, 0, NN * sizeof(int), stream);
    place_kernel<<<(NE + 255) / 256, 256, 0, stream>>>(src, dst, edge_types, rm, rp, fill,
                                                       csr_s, csr_w);
    embed_kernel<<<NPAD * 16 / 256, 256, 0, stream>>>(node_ids, embed_table, xH, xL);
    wprep_kernel<<<640, 256, 0, stream>>>(Wih, Whh, ggnn_w, WB);
    // zero pad region of x2 planes (last memory tile) so gemm A-reads of pad rows are 0
    hipMemsetAsync(x2H + (size_t)(NT - 1) * 16384, 0, 16384 * sizeof(ush_t), stream);
    hipMemsetAsync(x2L + (size_t)(NT - 1) * 16384, 0, 16384 * sizeof(ush_t), stream);

    // 4 GGNN layers
    for (int layer = 0; layer < 4; ++layer) {
        gemm_mfma_kernel<<<NT2, 256, 0, stream>>>(xH, xL, WB, 6 + layer, mRM);
        agg_kernel<<<(NPAD + 7) / 8, 256, 0, stream>>>(mRM, rp, csr_s, csr_w, agH, agL);
        gru_mfma_kernel<<<NT2, 256, 0, stream>>>(agH, agL, xH, xL, WB, bih, bhh, x2H, x2L);
        ush_t* th = xH; xH = x2H; x2H = th;
        ush_t* tl = xL; xL = x2L; x2L = tl;
    }

    // global attention pooling
    hipMemsetAsync(accum, 0, (DD + 1) * sizeof(float), stream);
    pool_kernel<<<NT, 256, 0, stream>>>(xH, xL, gate_w, gate_b, accum, den);
    finalize_kernel<<<1, 128, 0, stream>>>(accum, den, out);
}

// Round 7
// 1110.683 us; speedup vs baseline: 1.4902x; 1.4902x over previous
//
#include <hip/hip_runtime.h>
#include <math.h>

#define NN 100000
#define NPAD 100096
#define NT 782        // NPAD / 128  (memory tiles)
#define NT2 1564      // NPAD / 64   (gemm/gru blocks)
#define NE 800000
#define DD 128

typedef __attribute__((ext_vector_type(8))) short short8;
typedef __attribute__((ext_vector_type(4))) float floatx4;
typedef unsigned short ush_t;
typedef __attribute__((ext_vector_type(8))) unsigned short ushort8_t;

__device__ __forceinline__ ush_t f2bf(float f) {
    unsigned u = __float_as_uint(f);
    return (ush_t)((u + 0x7fffu + ((u >> 16) & 1u)) >> 16);
}
__device__ __forceinline__ float bf2f(ush_t h) {
    return __uint_as_float((unsigned)h << 16);
}
__device__ __forceinline__ void split2(float f, ush_t* H, ush_t* L) {
    ush_t h = f2bf(f);
    *H = h;
    *L = f2bf(f - bf2f(h));
}
__device__ __forceinline__ float sigf(float x) {
    return __builtin_amdgcn_rcpf(1.0f + __expf(-x));
}
__device__ __forceinline__ float tanhf_fast(float x) {
    x = fminf(fmaxf(x, -20.0f), 20.0f);
    float e = __expf(2.0f * x);
    return 1.0f - 2.0f * __builtin_amdgcn_rcpf(e + 1.0f);
}

// ---------------------------------------------------------------- row means of edge-type table
__global__ void rowmean_kernel(const float* __restrict__ tab, float* __restrict__ rm) {
    int r = blockIdx.x;
    int t = threadIdx.x;
    float v = tab[r * DD + t];
    #pragma unroll
    for (int o = 32; o > 0; o >>= 1) v += __shfl_xor(v, o);
    __shared__ float red[2];
    if ((t & 63) == 0) red[t >> 6] = v;
    __syncthreads();
    if (t == 0) rm[r] = (red[0] + red[1]) * (1.0f / DD);
}

// ---------------------------------------------------------------- CSR build
__global__ void hist_kernel(const int* __restrict__ dst, int* __restrict__ fill) {
    int e = blockIdx.x * 256 + threadIdx.x;
    if (e < NE) atomicAdd(&fill[dst[e]], 1);
}

__global__ __launch_bounds__(1024) void scan_kernel(const int* __restrict__ cnt,
                                                    int* __restrict__ rp) {
    __shared__ int wsum[16];
    __shared__ int carry_s;
    int t = threadIdx.x;
    int lane = t & 63, w = t >> 6;
    if (t == 0) { carry_s = 0; rp[0] = 0; }
    __syncthreads();
    for (int base = 0; base < NN; base += 1024) {
        int i = base + t;
        int v = (i < NN) ? cnt[i] : 0;
        int sv = v;
        #pragma unroll
        for (int off = 1; off < 64; off <<= 1) {
            int u = __shfl_up(sv, off);
            if (lane >= off) sv += u;
        }
        if (lane == 63) wsum[w] = sv;
        __syncthreads();
        int woff = carry_s;
        for (int j = 0; j < w; ++j) woff += wsum[j];
        if (i < NN) rp[i + 1] = sv + woff;
        __syncthreads();
        if (t == 0) {
            int tot = 0;
            for (int j = 0; j < 16; ++j) tot += wsum[j];
            carry_s += tot;
        }
        __syncthreads();
    }
}

__global__ void place_kernel(const int* __restrict__ src, const int* __restrict__ dst,
                             const int* __restrict__ et, const float* __restrict__ rm,
                             const int* __restrict__ rp, int* __restrict__ fill,
                             int* __restrict__ csr_s, float* __restrict__ csr_w) {
    int e = blockIdx.x * 256 + threadIdx.x;
    if (e < NE) {
        int d = dst[e];
        int pos = rp[d] + atomicAdd(&fill[d], 1);
        csr_s[pos] = src[e];
        csr_w[pos] = rm[et[e] - 1];
    }
}

// ---------------------------------------------------------------- embedding gather → H/L planes
__global__ void embed_kernel(const int* __restrict__ ids, const float* __restrict__ tab,
                             ush_t* __restrict__ xH, ush_t* __restrict__ xL) {
    int tid = blockIdx.x * 256 + threadIdx.x;   // NPAD*16
    int n = tid >> 4, c = tid & 15;
    if (n >= NPAD) return;
    int k = c * 8;
    int base = ((n >> 7) << 14) + ((k >> 5) << 12) + (((n >> 4) & 7) << 9)
             + (((k >> 3) & 3) << 7) + ((n & 15) << 3);
    ushort4 h0, h1, l0, l1;
    if (n < NN) {
        const float4* srcp = (const float4*)(tab + (size_t)(ids[n] + 1) * DD + k);
        float4 v0 = srcp[0], v1 = srcp[1];
        split2(v0.x, &h0.x, &l0.x); split2(v0.y, &h0.y, &l0.y);
        split2(v0.z, &h0.z, &l0.z); split2(v0.w, &h0.w, &l0.w);
        split2(v1.x, &h1.x, &l1.x); split2(v1.y, &h1.y, &l1.y);
        split2(v1.z, &h1.z, &l1.z); split2(v1.w, &h1.w, &l1.w);
    } else {
        h0 = make_ushort4(0, 0, 0, 0); h1 = h0; l0 = h0; l1 = h0;
    }
    *(ushort4*)(xH + base) = h0; *(ushort4*)(xH + base + 4) = h1;
    *(ushort4*)(xL + base) = l0; *(ushort4*)(xL + base + 4) = l1;
}

// ---------------------------------------------------------------- weight prep
// mats 0..2: Whh gates r,z,n | 3..5: Wih gates r,z,n | 6..9: ggnn layer W
__global__ void wprep_kernel(const float* __restrict__ Wih, const float* __restrict__ Whh,
                             const float* __restrict__ G, ush_t* __restrict__ WB) {
    int idx = blockIdx.x * 256 + threadIdx.x;   // 10*16384
    int mat = idx >> 14;
    int rem = idx & 16383;
    int col = rem & 127, kk = rem >> 7;
    float w;
    if (mat < 3)      w = Whh[((size_t)mat * 128 + col) * 128 + kk];
    else if (mat < 6) w = Wih[((size_t)(mat - 3) * 128 + col) * 128 + kk];
    else              w = G[(size_t)(mat - 6) * 16384 + (size_t)kk * 128 + col];
    int chunk = kk >> 5, klo = kk & 31;
    int inoff = ((col >> 4) * 4 + (klo >> 3)) * 128 + (col & 15) * 8 + (klo & 7);
    ush_t h, l;
    split2(w, &h, &l);
    size_t base = (size_t)((mat * 4 + chunk) * 2) * 4096;
    WB[base + inoff] = h;
    WB[base + 4096 + inoff] = l;
}

// ---------------------------------------------------------------- m = x @ W  (MFMA, LDS-staged output)
// reads x H/L planes (frag order), writes ROW-MAJOR bf16 m via coalesced 16B stores
__global__ __launch_bounds__(256, 4) void gemm_mfma_kernel(const ush_t* __restrict__ xH,
                                                           const ush_t* __restrict__ xL,
                                                           const ush_t* __restrict__ WB,
                                                           int mat, ush_t* __restrict__ mRM) {
    __shared__ float sM[64 * 132];
    int t = threadIdx.x;
    int tb = blockIdx.x;                 // 64-row tile
    int l = t & 63, w = t >> 6;          // w = colgrp 0..3
    int lg = l >> 4, lc = l & 15;
    floatx4 acc[4][2];
    #pragma unroll
    for (int i = 0; i < 4; ++i)
        #pragma unroll
        for (int j = 0; j < 2; ++j) acc[i][j] = (floatx4)0.f;
    int abase = (tb >> 1) * 16384 + (tb & 1) * 2048 + lg * 128 + lc * 8;
    #pragma unroll
    for (int kc = 0; kc < 4; ++kc) {
        short8 aH[4], aL[4];
        #pragma unroll
        for (int i = 0; i < 4; ++i) {
            int off = abase + kc * 4096 + i * 512;
            aH[i] = *(const short8*)(xH + off);
            aL[i] = *(const short8*)(xL + off);
        }
        #pragma unroll
        for (int j = 0; j < 2; ++j) {
            int boff = (((w * 2 + j) * 4 + lg) * 16 + lc) * 8;
            const ush_t* wb = WB + (size_t)((mat * 4 + kc) * 2) * 4096;
            short8 bH = *(const short8*)(wb + boff);
            short8 bL = *(const short8*)(wb + 4096 + boff);
            #pragma unroll
            for (int i = 0; i < 4; ++i) {
                acc[i][j] = __builtin_amdgcn_mfma_f32_16x16x32_bf16(aH[i], bH, acc[i][j], 0, 0, 0);
                acc[i][j] = __builtin_amdgcn_mfma_f32_16x16x32_bf16(aH[i], bL, acc[i][j], 0, 0, 0);
                acc[i][j] = __builtin_amdgcn_mfma_f32_16x16x32_bf16(aL[i], bH, acc[i][j], 0, 0, 0);
            }
        }
    }
    // scatter C-frags to LDS (2-way bank alias only — free)
    #pragma unroll
    for (int j = 0; j < 2; ++j)
        #pragma unroll
        for (int i = 0; i < 4; ++i)
            #pragma unroll
            for (int r = 0; r < 4; ++r)
                sM[(i * 16 + lg * 4 + r) * 132 + w * 32 + j * 16 + lc] = acc[i][j][r];
    __syncthreads();
    // linear coalesced write-out
    int t4 = t >> 4, tl = t & 15;
    #pragma unroll
    for (int jj = 0; jj < 4; ++jj) {
        const float* srcp = &sM[(jj * 16 + t4) * 132 + tl * 8];
        ushort8_t o;
        #pragma unroll
        for (int e = 0; e < 8; ++e) o[e] = f2bf(srcp[e]);
        *(ushort8_t*)(mRM + (size_t)tb * 8192 + jj * 2048 + t * 8) = o;
    }
}

// ---------------------------------------------------------------- CSR aggregation
// reads bf16 row-major m (256 B/edge), writes agg H/L planes (frag order)
__global__ __launch_bounds__(512) void agg_kernel(const ush_t* __restrict__ m,
                                                  const int* __restrict__ rp,
                                                  const int* __restrict__ csr_s,
                                                  const float* __restrict__ csr_w,
                                                  ush_t* __restrict__ aggH,
                                                  ush_t* __restrict__ aggL) {
    int t = threadIdx.x;
    int grp = t >> 5, c = t & 31;
    int n = blockIdx.x * 16 + grp;
    if (n >= NPAD) return;
    int nout = ((n >> 7) << 14) + ((c >> 3) << 12) + (((n >> 4) & 7) << 9)
             + (((c >> 1) & 3) << 7) + ((n & 15) << 3) + ((c & 1) << 2);
    ushort4 zh = make_ushort4(0, 0, 0, 0);
    if (n >= NN) {
        *(ushort4*)(aggH + nout) = zh;
        *(ushort4*)(aggL + nout) = zh;
        return;
    }
    int e0 = rp[n], e1 = rp[n + 1];
    float4 acc = make_float4(0.f, 0.f, 0.f, 0.f);
    for (int e = e0; e < e1; ++e) {
        float w0 = csr_w[e];
        int s0 = csr_s[e];
        ushort4 p = *(const ushort4*)(m + (size_t)s0 * DD + c * 4);
        acc.x += w0 * bf2f(p.x);
        acc.y += w0 * bf2f(p.y);
        acc.z += w0 * bf2f(p.z);
        acc.w += w0 * bf2f(p.w);
    }
    ushort4 oh, ol;
    split2(acc.x, &oh.x, &ol.x); split2(acc.y, &oh.y, &ol.y);
    split2(acc.z, &oh.z, &ol.z); split2(acc.w, &oh.w, &ol.w);
    *(ushort4*)(aggH + nout) = oh;
    *(ushort4*)(aggL + nout) = ol;
}

// ---------------------------------------------------------------- fused GRU (MFMA, LDS-staged output)
// pass 0: A = x vs Whh (mats 0..2) → accR,accZ,accN ; pass 1: A = agg vs Wih (3..5) → accR,accZ,accI
__global__ __launch_bounds__(256, 2) void gru_mfma_kernel(const ush_t* __restrict__ aggH,
                                                          const ush_t* __restrict__ aggL,
                                                          const ush_t* __restrict__ xH,
                                                          const ush_t* __restrict__ xL,
                                                          const ush_t* __restrict__ WB,
                                                          const float* __restrict__ bih,
                                                          const float* __restrict__ bhh,
                                                          ush_t* __restrict__ xoH,
                                                          ush_t* __restrict__ xoL) {
    __shared__ float sV[64 * 132];
    int t = threadIdx.x;
    int tb = blockIdx.x;                 // 64-row tile
    int l = t & 63, w = t >> 6;          // w = colgrp
    int lg = l >> 4, lc = l & 15;
    floatx4 accR[4][2], accZ[4][2], accN[4][2], accI[4][2];
    #pragma unroll
    for (int i = 0; i < 4; ++i)
        #pragma unroll
        for (int j = 0; j < 2; ++j) {
            accR[i][j] = (floatx4)0.f; accZ[i][j] = (floatx4)0.f;
            accN[i][j] = (floatx4)0.f; accI[i][j] = (floatx4)0.f;
        }
    int abase = (tb >> 1) * 16384 + (tb & 1) * 2048 + lg * 128 + lc * 8;
    #pragma unroll
    for (int pass = 0; pass < 2; ++pass) {
        const ush_t* ApH = pass ? aggH : xH;
        const ush_t* ApL = pass ? aggL : xL;
        int matbase = pass ? 3 : 0;
        #pragma unroll
        for (int kc = 0; kc < 4; ++kc) {
            short8 aHf[4], aLf[4];
            #pragma unroll
            for (int i = 0; i < 4; ++i) {
                int off = abase + kc * 4096 + i * 512;
                aHf[i] = *(const short8*)(ApH + off);
                aLf[i] = *(const short8*)(ApL + off);
            }
            #pragma unroll
            for (int m3 = 0; m3 < 3; ++m3) {
                floatx4 (*accp)[2] = (m3 == 0) ? accR : (m3 == 1) ? accZ : (pass ? accI : accN);
                const ush_t* wb = WB + (size_t)(((matbase + m3) * 4 + kc) * 2) * 4096;
                #pragma unroll
                for (int j = 0; j < 2; ++j) {
                    int boff = (((w * 2 + j) * 4 + lg) * 16 + lc) * 8;
                    short8 bH = *(const short8*)(wb + boff);
                    short8 bL = *(const short8*)(wb + 4096 + boff);
                    #pragma unroll
                    for (int i = 0; i < 4; ++i) {
                        accp[i][j] = __builtin_amdgcn_mfma_f32_16x16x32_bf16(aHf[i], bH, accp[i][j], 0, 0, 0);
                        accp[i][j] = __builtin_amdgcn_mfma_f32_16x16x32_bf16(aHf[i], bL, accp[i][j], 0, 0, 0);
                        accp[i][j] = __builtin_amdgcn_mfma_f32_16x16x32_bf16(aLf[i], bH, accp[i][j], 0, 0, 0);
                    }
                }
            }
        }
    }
    // scatter phase: gates + blend (h reload is L1/L2-hot — just streamed by pass-0 A-loads)
    #pragma unroll
    for (int j = 0; j < 2; ++j) {
        int col = w * 32 + j * 16 + lc;
        float bIr = bih[col],       bHr = bhh[col];
        float bIz = bih[128 + col], bHz = bhh[128 + col];
        float bIn = bih[256 + col], bHn = bhh[256 + col];
        int cpart = w * 4096 + (j * 2 + (lc >> 3)) * 128 + (lc & 7);
        #pragma unroll
        for (int i = 0; i < 4; ++i)
            #pragma unroll
            for (int r = 0; r < 4; ++r) {
                int row = tb * 64 + i * 16 + lg * 4 + r;
                float v = 0.f;
                if (row < NN) {
                    int idx = (tb >> 1) * 16384 + ((tb & 1) * 4 + i) * 512
                            + (lg * 4 + r) * 8 + cpart;
                    float rr = sigf(accR[i][j][r] + bIr + bHr);
                    float zz = sigf(accZ[i][j][r] + bIz + bHz);
                    float nn = tanhf_fast(accI[i][j][r] + bIn + rr * (accN[i][j][r] + bHn));
                    float h = bf2f(xH[idx]) + bf2f(xL[idx]);
                    v = (1.0f - zz) * nn + zz * h;
                }
                sV[(i * 16 + lg * 4 + r) * 132 + col] = v;
            }
    }
    __syncthreads();
    // linear coalesced write-out to frag planes (wave covers aligned 64B chunks)
    int t4 = t >> 4, tl = t & 15;
    #pragma unroll
    for (int jj = 0; jj < 4; ++jj) {
        const float* srcp = &sV[(jj * 16 + t4) * 132 + tl * 8];
        ushort8_t oh, ol;
        #pragma unroll
        for (int e = 0; e < 8; ++e) {
            ush_t H, L;
            split2(srcp[e], &H, &L);
            oh[e] = H; ol[e] = L;
        }
        int oidx = (tb >> 1) * 16384 + (tl >> 2) * 4096 + ((tb & 1) * 4 + jj) * 512
                 + (tl & 3) * 128 + t4 * 8;
        *(ushort8_t*)(xoH + oidx) = oh;
        *(ushort8_t*)(xoL + oidx) = ol;
    }
}

// ---------------------------------------------------------------- fused pooling (tile-based, planes)
__global__ __launch_bounds__(256) void pool_kernel(const ush_t* __restrict__ xH,
                                                   const ush_t* __restrict__ xL,
                                                   const float* __restrict__ gw,
                                                   const float* __restrict__ gb,
                                                   float* __restrict__ accum,
                                                   float* __restrict__ den) {
    __shared__ float sgw[128];
    __shared__ float rowsum[128];
    __shared__ float pl[128];
    __shared__ float acc2[128];
    int t = threadIdx.x;
    int tb = blockIdx.x;                 // 128-row memory tile
    if (t < 128) { sgw[t] = gw[t]; rowsum[t] = 0.f; acc2[t] = 0.f; }
    __syncthreads();
    const ush_t* xh = xH + (size_t)tb * 16384;
    const ush_t* xl = xL + (size_t)tb * 16384;
    int kc = t >> 6, rg = (t >> 3) & 7, cb = (t >> 1) & 3, rlh = t & 1;
    int colb = kc * 32 + cb * 8;
    float fv[8][8];
    float g[8];
    #pragma unroll
    for (int e = 0; e < 8; ++e) g[e] = sgw[colb + e];
    #pragma unroll
    for (int jh = 0; jh < 8; ++jh) {
        int base = t * 64 + jh * 8;
        short8 a = *(const short8*)(xh + base);
        short8 b = *(const short8*)(xl + base);
        float s = 0.f;
        #pragma unroll
        for (int e = 0; e < 8; ++e) {
            float f = bf2f((ush_t)a[e]) + bf2f((ush_t)b[e]);
            fv[jh][e] = f;
            s += f * g[e];
        }
        atomicAdd(&rowsum[rg * 16 + rlh * 8 + jh], s);
    }
    __syncthreads();
    if (t < 128) {
        int row = tb * 128 + t;
        float pv = 0.f;
        if (row < NN) pv = __expf(sigf(rowsum[t] + gb[0]));
        pl[t] = pv;
    }
    __syncthreads();
    float wsv[8];
    #pragma unroll
    for (int e = 0; e < 8; ++e) wsv[e] = 0.f;
    #pragma unroll
    for (int jh = 0; jh < 8; ++jh) {
        float pv = pl[rg * 16 + rlh * 8 + jh];
        #pragma unroll
        for (int e = 0; e < 8; ++e) wsv[e] += pv * fv[jh][e];
    }
    #pragma unroll
    for (int e = 0; e < 8; ++e) atomicAdd(&acc2[colb + e], wsv[e]);
    __syncthreads();
    if (t < 128) atomicAdd(&accum[t], acc2[t]);
    if (t < 64) {
        float v = pl[t] + pl[t + 64];
        #pragma unroll
        for (int o = 32; o > 0; o >>= 1) v += __shfl_xor(v, o);
        if (t == 0) atomicAdd(den, v);
    }
}

__global__ void finalize_kernel(const float* __restrict__ accum, const float* __restrict__ den,
                                float* __restrict__ out) {
    out[threadIdx.x] = accum[threadIdx.x] / den[0];
}

// ---------------------------------------------------------------- launch
extern "C" void kernel_launch(void* const* d_in, const int* in_sizes, int n_in,
                              void* d_out, int out_size, void* d_ws, size_t ws_size,
                              hipStream_t stream) {
    const int*   node_ids    = (const int*)d_in[0];
    const int*   edges       = (const int*)d_in[1];
    const int*   edge_types  = (const int*)d_in[2];
    const float* embed_table = (const float*)d_in[3];
    const float* edge_tab    = (const float*)d_in[4];
    const float* ggnn_w      = (const float*)d_in[5];
    const float* Wih         = (const float*)d_in[6];
    const float* Whh         = (const float*)d_in[7];
    const float* bih         = (const float*)d_in[8];
    const float* bhh         = (const float*)d_in[9];
    const float* gate_w      = (const float*)d_in[10];
    const float* gate_b      = (const float*)d_in[11];
    float* out = (float*)d_out;

    const size_t PL = (size_t)NPAD * DD;       // plane elems
    ush_t* wsb  = (ush_t*)d_ws;
    ush_t* xH   = wsb;             ush_t* xL   = xH + PL;
    ush_t* x2H  = xL + PL;         ush_t* x2L  = x2H + PL;
    ush_t* agH  = x2L + PL;        ush_t* agL  = agH + PL;
    ush_t* mRM  = agL + PL;        // single plane, row-major
    ush_t* WB   = mRM + PL;        // 10*4*2*4096
    float* csr_w = (float*)(WB + 10 * 4 * 2 * 4096);
    float* accum = csr_w + NE;     // 128
    float* den   = accum + DD;     // 1
    float* rm    = den + 1;        // 7(+1)
    int*   rp    = (int*)(rm + 8); // N+1
    int*   fill  = rp + NN + 1;    // N
    int*   csr_s = fill + NN;      // E

    const int* src = edges;
    const int* dst = edges + NE;

    // one-time prep
    rowmean_kernel<<<7, 128, 0, stream>>>(edge_tab, rm);
    hipMemsetAsync(fill, 0, NN * sizeof(int), stream);
    hist_kernel<<<(NE + 255) / 256, 256, 0, stream>>>(dst, fill);
    scan_kernel<<<1, 1024, 0, stream>>>(fill, rp);
    hipMemsetAsync(fill, 0, NN * sizeof(int), stream);
    place_kernel<<<(NE + 255) / 256, 256, 0, stream>>>(src, dst, edge_types, rm, rp, fill,
                                                       csr_s, csr_w);
    embed_kernel<<<NPAD * 16 / 256, 256, 0, stream>>>(node_ids, embed_table, xH, xL);
    wprep_kernel<<<640, 256, 0, stream>>>(Wih, Whh, ggnn_w, WB);

    // 4 GGNN layers
    for (int layer = 0; layer < 4; ++layer) {
        gemm_mfma_kernel<<<NT2, 256, 0, stream>>>(xH, xL, WB, 6 + layer, mRM);
        agg_kernel<<<(NPAD + 15) / 16, 512, 0, stream>>>(mRM, rp, csr_s, csr_w, agH, agL);
        gru_mfma_kernel<<<NT2, 256, 0, stream>>>(agH, agL, xH, xL, WB, bih, bhh, x2H, x2L);
        ush_t* th = xH; xH = x2H; x2H = th;
        ush_t* tl = xL; xL = x2L; x2L = tl;
    }

    // global attention pooling
    hipMemsetAsync(accum, 0, (DD + 1) * sizeof(float), stream);
    pool_kernel<<<NT, 256, 0, stream>>>(xH, xL, gate_w, gate_b, accum, den);
    finalize_kernel<<<1, 128, 0, stream>>>(accum, den, out);
}

// Round 8
// 1005.195 us; speedup vs baseline: 1.6466x; 1.1049x over previous
//
#include <hip/hip_runtime.h>
#include <math.h>

#define NN 100000
#define NPAD 100096
#define NT 782        // NPAD / 128  (memory tiles)
#define NT2 1564      // NPAD / 64   (gemm/gru blocks)
#define NE 800000
#define DD 128
#define SCANB 98      // ceil(NN/1024)

typedef __attribute__((ext_vector_type(8))) short short8;
typedef __attribute__((ext_vector_type(4))) float floatx4;
typedef unsigned short ush_t;
typedef __attribute__((ext_vector_type(8))) unsigned short ushort8_t;

__device__ __forceinline__ ush_t f2bf(float f) {
    unsigned u = __float_as_uint(f);
    return (ush_t)((u + 0x7fffu + ((u >> 16) & 1u)) >> 16);
}
__device__ __forceinline__ float bf2f(ush_t h) {
    return __uint_as_float((unsigned)h << 16);
}
__device__ __forceinline__ void split2(float f, ush_t* H, ush_t* L) {
    ush_t h = f2bf(f);
    *H = h;
    *L = f2bf(f - bf2f(h));
}
__device__ __forceinline__ float sigf(float x) {
    return __builtin_amdgcn_rcpf(1.0f + __expf(-x));
}
__device__ __forceinline__ float tanhf_fast(float x) {
    x = fminf(fmaxf(x, -20.0f), 20.0f);
    float e = __expf(2.0f * x);
    return 1.0f - 2.0f * __builtin_amdgcn_rcpf(e + 1.0f);
}

// ---------------------------------------------------------------- row means of edge-type table
__global__ void rowmean_kernel(const float* __restrict__ tab, float* __restrict__ rm) {
    int r = blockIdx.x;
    int t = threadIdx.x;
    float v = tab[r * DD + t];
    #pragma unroll
    for (int o = 32; o > 0; o >>= 1) v += __shfl_xor(v, o);
    __shared__ float red[2];
    if ((t & 63) == 0) red[t >> 6] = v;
    __syncthreads();
    if (t == 0) rm[r] = (red[0] + red[1]) * (1.0f / DD);
}

// ---------------------------------------------------------------- CSR build
__global__ void hist_kernel(const int* __restrict__ dst, int* __restrict__ fill) {
    int e = blockIdx.x * 256 + threadIdx.x;
    if (e < NE) atomicAdd(&fill[dst[e]], 1);
}

// hierarchical scan: A = per-block inclusive scan + block totals
__global__ __launch_bounds__(1024) void scanA_kernel(const int* __restrict__ cnt,
                                                     int* __restrict__ rp,
                                                     int* __restrict__ bsum) {
    __shared__ int wsum[16];
    int t = threadIdx.x;
    int i = blockIdx.x * 1024 + t;
    int lane = t & 63, w = t >> 6;
    int v = (i < NN) ? cnt[i] : 0;
    int sv = v;
    #pragma unroll
    for (int off = 1; off < 64; off <<= 1) {
        int u = __shfl_up(sv, off);
        if (lane >= off) sv += u;
    }
    if (lane == 63) wsum[w] = sv;
    __syncthreads();
    int woff = 0;
    #pragma unroll
    for (int j = 0; j < 16; ++j) woff += (j < w) ? wsum[j] : 0;
    if (i < NN) rp[i + 1] = sv + woff;
    if (t == 1023) bsum[blockIdx.x] = sv + woff;
}

// B = exclusive scan of the block totals (1 small block)
__global__ __launch_bounds__(128) void scanB_kernel(const int* __restrict__ bsum,
                                                    int* __restrict__ boff) {
    __shared__ int wsum[2];
    int t = threadIdx.x;
    int lane = t & 63, w = t >> 6;
    int v = (t < SCANB) ? bsum[t] : 0;
    int sv = v;
    #pragma unroll
    for (int off = 1; off < 64; off <<= 1) {
        int u = __shfl_up(sv, off);
        if (lane >= off) sv += u;
    }
    if (lane == 63) wsum[w] = sv;
    __syncthreads();
    int woff = (w == 1) ? wsum[0] : 0;
    if (t < SCANB) boff[t] = sv + woff - v;   // exclusive
}

// C = add block offsets
__global__ __launch_bounds__(256) void scanC_kernel(int* __restrict__ rp,
                                                    const int* __restrict__ boff) {
    int i = blockIdx.x * 256 + threadIdx.x;
    if (i == 0) rp[0] = 0;
    if (i < NN) rp[i + 1] += boff[i >> 10];
}

__global__ void place_kernel(const int* __restrict__ src, const int* __restrict__ dst,
                             const int* __restrict__ et, const float* __restrict__ rm,
                             const int* __restrict__ rp, int* __restrict__ fill,
                             int* __restrict__ csr_s, float* __restrict__ csr_w) {
    int e = blockIdx.x * 256 + threadIdx.x;
    if (e < NE) {
        int d = dst[e];
        int pos = rp[d] + atomicAdd(&fill[d], 1);
        csr_s[pos] = src[e];
        csr_w[pos] = rm[et[e] - 1];
    }
}

// ---------------------------------------------------------------- embedding gather → H/L planes
__global__ void embed_kernel(const int* __restrict__ ids, const float* __restrict__ tab,
                             ush_t* __restrict__ xH, ush_t* __restrict__ xL) {
    int tid = blockIdx.x * 256 + threadIdx.x;   // NPAD*16
    int n = tid >> 4, c = tid & 15;
    if (n >= NPAD) return;
    int k = c * 8;
    int base = ((n >> 7) << 14) + ((k >> 5) << 12) + (((n >> 4) & 7) << 9)
             + (((k >> 3) & 3) << 7) + ((n & 15) << 3);
    ushort4 h0, h1, l0, l1;
    if (n < NN) {
        const float4* srcp = (const float4*)(tab + (size_t)(ids[n] + 1) * DD + k);
        float4 v0 = srcp[0], v1 = srcp[1];
        split2(v0.x, &h0.x, &l0.x); split2(v0.y, &h0.y, &l0.y);
        split2(v0.z, &h0.z, &l0.z); split2(v0.w, &h0.w, &l0.w);
        split2(v1.x, &h1.x, &l1.x); split2(v1.y, &h1.y, &l1.y);
        split2(v1.z, &h1.z, &l1.z); split2(v1.w, &h1.w, &l1.w);
    } else {
        h0 = make_ushort4(0, 0, 0, 0); h1 = h0; l0 = h0; l1 = h0;
    }
    *(ushort4*)(xH + base) = h0; *(ushort4*)(xH + base + 4) = h1;
    *(ushort4*)(xL + base) = l0; *(ushort4*)(xL + base + 4) = l1;
}

// ---------------------------------------------------------------- weight prep
// mats 0..2: Whh gates r,z,n | 3..5: Wih gates r,z,n | 6..9: ggnn layer W
__global__ void wprep_kernel(const float* __restrict__ Wih, const float* __restrict__ Whh,
                             const float* __restrict__ G, ush_t* __restrict__ WB) {
    int idx = blockIdx.x * 256 + threadIdx.x;   // 10*16384
    int mat = idx >> 14;
    int rem = idx & 16383;
    int col = rem & 127, kk = rem >> 7;
    float w;
    if (mat < 3)      w = Whh[((size_t)mat * 128 + col) * 128 + kk];
    else if (mat < 6) w = Wih[((size_t)(mat - 3) * 128 + col) * 128 + kk];
    else              w = G[(size_t)(mat - 6) * 16384 + (size_t)kk * 128 + col];
    int chunk = kk >> 5, klo = kk & 31;
    int inoff = ((col >> 4) * 4 + (klo >> 3)) * 128 + (col & 15) * 8 + (klo & 7);
    ush_t h, l;
    split2(w, &h, &l);
    size_t base = (size_t)((mat * 4 + chunk) * 2) * 4096;
    WB[base + inoff] = h;
    WB[base + 4096 + inoff] = l;
}

// ---------------------------------------------------------------- m = x @ W  (MFMA, LDS-staged output)
__global__ __launch_bounds__(256, 4) void gemm_mfma_kernel(const ush_t* __restrict__ xH,
                                                           const ush_t* __restrict__ xL,
                                                           const ush_t* __restrict__ WB,
                                                           int mat, ush_t* __restrict__ mRM) {
    __shared__ float sM[64 * 132];
    int t = threadIdx.x;
    int tb = blockIdx.x;                 // 64-row tile
    int l = t & 63, w = t >> 6;          // w = colgrp 0..3
    int lg = l >> 4, lc = l & 15;
    floatx4 acc[4][2];
    #pragma unroll
    for (int i = 0; i < 4; ++i)
        #pragma unroll
        for (int j = 0; j < 2; ++j) acc[i][j] = (floatx4)0.f;
    int abase = (tb >> 1) * 16384 + (tb & 1) * 2048 + lg * 128 + lc * 8;
    #pragma unroll
    for (int kc = 0; kc < 4; ++kc) {
        short8 aH[4], aL[4];
        #pragma unroll
        for (int i = 0; i < 4; ++i) {
            int off = abase + kc * 4096 + i * 512;
            aH[i] = *(const short8*)(xH + off);
            aL[i] = *(const short8*)(xL + off);
        }
        #pragma unroll
        for (int j = 0; j < 2; ++j) {
            int boff = (((w * 2 + j) * 4 + lg) * 16 + lc) * 8;
            const ush_t* wb = WB + (size_t)((mat * 4 + kc) * 2) * 4096;
            short8 bH = *(const short8*)(wb + boff);
            short8 bL = *(const short8*)(wb + 4096 + boff);
            #pragma unroll
            for (int i = 0; i < 4; ++i) {
                acc[i][j] = __builtin_amdgcn_mfma_f32_16x16x32_bf16(aH[i], bH, acc[i][j], 0, 0, 0);
                acc[i][j] = __builtin_amdgcn_mfma_f32_16x16x32_bf16(aH[i], bL, acc[i][j], 0, 0, 0);
                acc[i][j] = __builtin_amdgcn_mfma_f32_16x16x32_bf16(aL[i], bH, acc[i][j], 0, 0, 0);
            }
        }
    }
    // scatter C-frags to LDS (2-way bank alias only — free)
    #pragma unroll
    for (int j = 0; j < 2; ++j)
        #pragma unroll
        for (int i = 0; i < 4; ++i)
            #pragma unroll
            for (int r = 0; r < 4; ++r)
                sM[(i * 16 + lg * 4 + r) * 132 + w * 32 + j * 16 + lc] = acc[i][j][r];
    __syncthreads();
    // linear coalesced write-out
    int t4 = t >> 4, tl = t & 15;
    #pragma unroll
    for (int jj = 0; jj < 4; ++jj) {
        const float* srcp = &sM[(jj * 16 + t4) * 132 + tl * 8];
        ushort8_t o;
        #pragma unroll
        for (int e = 0; e < 8; ++e) o[e] = f2bf(srcp[e]);
        *(ushort8_t*)(mRM + (size_t)tb * 8192 + jj * 2048 + t * 8) = o;
    }
}

// ---------------------------------------------------------------- CSR aggregation
__global__ __launch_bounds__(512) void agg_kernel(const ush_t* __restrict__ m,
                                                  const int* __restrict__ rp,
                                                  const int* __restrict__ csr_s,
                                                  const float* __restrict__ csr_w,
                                                  ush_t* __restrict__ aggH,
                                                  ush_t* __restrict__ aggL) {
    int t = threadIdx.x;
    int grp = t >> 5, c = t & 31;
    int n = blockIdx.x * 16 + grp;
    if (n >= NPAD) return;
    int nout = ((n >> 7) << 14) + ((c >> 3) << 12) + (((n >> 4) & 7) << 9)
             + (((c >> 1) & 3) << 7) + ((n & 15) << 3) + ((c & 1) << 2);
    ushort4 zh = make_ushort4(0, 0, 0, 0);
    if (n >= NN) {
        *(ushort4*)(aggH + nout) = zh;
        *(ushort4*)(aggL + nout) = zh;
        return;
    }
    int e0 = rp[n], e1 = rp[n + 1];
    float4 acc = make_float4(0.f, 0.f, 0.f, 0.f);
    for (int e = e0; e < e1; ++e) {
        float w0 = csr_w[e];
        int s0 = csr_s[e];
        ushort4 p = *(const ushort4*)(m + (size_t)s0 * DD + c * 4);
        acc.x += w0 * bf2f(p.x);
        acc.y += w0 * bf2f(p.y);
        acc.z += w0 * bf2f(p.z);
        acc.w += w0 * bf2f(p.w);
    }
    ushort4 oh, ol;
    split2(acc.x, &oh.x, &ol.x); split2(acc.y, &oh.y, &ol.y);
    split2(acc.z, &oh.z, &ol.z); split2(acc.w, &oh.w, &ol.w);
    *(ushort4*)(aggH + nout) = oh;
    *(ushort4*)(aggL + nout) = ol;
}

// ---------------------------------------------------------------- fused GRU (MFMA, LDS-staged output)
__global__ __launch_bounds__(256, 2) void gru_mfma_kernel(const ush_t* __restrict__ aggH,
                                                          const ush_t* __restrict__ aggL,
                                                          const ush_t* __restrict__ xH,
                                                          const ush_t* __restrict__ xL,
                                                          const ush_t* __restrict__ WB,
                                                          const float* __restrict__ bih,
                                                          const float* __restrict__ bhh,
                                                          ush_t* __restrict__ xoH,
                                                          ush_t* __restrict__ xoL) {
    __shared__ float sV[64 * 132];
    int t = threadIdx.x;
    int tb = blockIdx.x;                 // 64-row tile
    int l = t & 63, w = t >> 6;          // w = colgrp
    int lg = l >> 4, lc = l & 15;
    floatx4 accR[4][2], accZ[4][2], accN[4][2], accI[4][2];
    #pragma unroll
    for (int i = 0; i < 4; ++i)
        #pragma unroll
        for (int j = 0; j < 2; ++j) {
            accR[i][j] = (floatx4)0.f; accZ[i][j] = (floatx4)0.f;
            accN[i][j] = (floatx4)0.f; accI[i][j] = (floatx4)0.f;
        }
    int abase = (tb >> 1) * 16384 + (tb & 1) * 2048 + lg * 128 + lc * 8;
    #pragma unroll
    for (int pass = 0; pass < 2; ++pass) {
        const ush_t* ApH = pass ? aggH : xH;
        const ush_t* ApL = pass ? aggL : xL;
        int matbase = pass ? 3 : 0;
        #pragma unroll
        for (int kc = 0; kc < 4; ++kc) {
            short8 aHf[4], aLf[4];
            #pragma unroll
            for (int i = 0; i < 4; ++i) {
                int off = abase + kc * 4096 + i * 512;
                aHf[i] = *(const short8*)(ApH + off);
                aLf[i] = *(const short8*)(ApL + off);
            }
            #pragma unroll
            for (int m3 = 0; m3 < 3; ++m3) {
                floatx4 (*accp)[2] = (m3 == 0) ? accR : (m3 == 1) ? accZ : (pass ? accI : accN);
                const ush_t* wb = WB + (size_t)(((matbase + m3) * 4 + kc) * 2) * 4096;
                #pragma unroll
                for (int j = 0; j < 2; ++j) {
                    int boff = (((w * 2 + j) * 4 + lg) * 16 + lc) * 8;
                    short8 bH = *(const short8*)(wb + boff);
                    short8 bL = *(const short8*)(wb + 4096 + boff);
                    #pragma unroll
                    for (int i = 0; i < 4; ++i) {
                        accp[i][j] = __builtin_amdgcn_mfma_f32_16x16x32_bf16(aHf[i], bH, accp[i][j], 0, 0, 0);
                        accp[i][j] = __builtin_amdgcn_mfma_f32_16x16x32_bf16(aHf[i], bL, accp[i][j], 0, 0, 0);
                        accp[i][j] = __builtin_amdgcn_mfma_f32_16x16x32_bf16(aLf[i], bH, accp[i][j], 0, 0, 0);
                    }
                }
            }
        }
    }
    // gates + blend → LDS (h reload is L1/L2-hot — just streamed by pass-0 A-loads)
    #pragma unroll
    for (int j = 0; j < 2; ++j) {
        int col = w * 32 + j * 16 + lc;
        float bIr = bih[col],       bHr = bhh[col];
        float bIz = bih[128 + col], bHz = bhh[128 + col];
        float bIn = bih[256 + col], bHn = bhh[256 + col];
        int cpart = w * 4096 + (j * 2 + (lc >> 3)) * 128 + (lc & 7);
        #pragma unroll
        for (int i = 0; i < 4; ++i)
            #pragma unroll
            for (int r = 0; r < 4; ++r) {
                int row = tb * 64 + i * 16 + lg * 4 + r;
                float v = 0.f;
                if (row < NN) {
                    int idx = (tb >> 1) * 16384 + ((tb & 1) * 4 + i) * 512
                            + (lg * 4 + r) * 8 + cpart;
                    float rr = sigf(accR[i][j][r] + bIr + bHr);
                    float zz = sigf(accZ[i][j][r] + bIz + bHz);
                    float nn = tanhf_fast(accI[i][j][r] + bIn + rr * (accN[i][j][r] + bHn));
                    float h = bf2f(xH[idx]) + bf2f(xL[idx]);
                    v = (1.0f - zz) * nn + zz * h;
                }
                sV[(i * 16 + lg * 4 + r) * 132 + col] = v;
            }
    }
    __syncthreads();
    // linear coalesced write-out to frag planes
    int t4 = t >> 4, tl = t & 15;
    #pragma unroll
    for (int jj = 0; jj < 4; ++jj) {
        const float* srcp = &sV[(jj * 16 + t4) * 132 + tl * 8];
        ushort8_t oh, ol;
        #pragma unroll
        for (int e = 0; e < 8; ++e) {
            ush_t H, L;
            split2(srcp[e], &H, &L);
            oh[e] = H; ol[e] = L;
        }
        int oidx = (tb >> 1) * 16384 + (tl >> 2) * 4096 + ((tb & 1) * 4 + jj) * 512
                 + (tl & 3) * 128 + t4 * 8;
        *(ushort8_t*)(xoH + oidx) = oh;
        *(ushort8_t*)(xoL + oidx) = ol;
    }
}

// ---------------------------------------------------------------- fused pooling (tile-based, planes)
__global__ __launch_bounds__(256) void pool_kernel(const ush_t* __restrict__ xH,
                                                   const ush_t* __restrict__ xL,
                                                   const float* __restrict__ gw,
                                                   const float* __restrict__ gb,
                                                   float* __restrict__ accum,
                                                   float* __restrict__ den) {
    __shared__ float sgw[128];
    __shared__ float rowsum[128];
    __shared__ float pl[128];
    __shared__ float acc2[128];
    int t = threadIdx.x;
    int tb = blockIdx.x;                 // 128-row memory tile
    if (t < 128) { sgw[t] = gw[t]; rowsum[t] = 0.f; acc2[t] = 0.f; }
    __syncthreads();
    const ush_t* xh = xH + (size_t)tb * 16384;
    const ush_t* xl = xL + (size_t)tb * 16384;
    int kc = t >> 6, rg = (t >> 3) & 7, cb = (t >> 1) & 3, rlh = t & 1;
    int colb = kc * 32 + cb * 8;
    float fv[8][8];
    float g[8];
    #pragma unroll
    for (int e = 0; e < 8; ++e) g[e] = sgw[colb + e];
    #pragma unroll
    for (int jh = 0; jh < 8; ++jh) {
        int base = t * 64 + jh * 8;
        short8 a = *(const short8*)(xh + base);
        short8 b = *(const short8*)(xl + base);
        float s = 0.f;
        #pragma unroll
        for (int e = 0; e < 8; ++e) {
            float f = bf2f((ush_t)a[e]) + bf2f((ush_t)b[e]);
            fv[jh][e] = f;
            s += f * g[e];
        }
        atomicAdd(&rowsum[rg * 16 + rlh * 8 + jh], s);
    }
    __syncthreads();
    if (t < 128) {
        int row = tb * 128 + t;
        float pv = 0.f;
        if (row < NN) pv = __expf(sigf(rowsum[t] + gb[0]));
        pl[t] = pv;
    }
    __syncthreads();
    float wsv[8];
    #pragma unroll
    for (int e = 0; e < 8; ++e) wsv[e] = 0.f;
    #pragma unroll
    for (int jh = 0; jh < 8; ++jh) {
        float pv = pl[rg * 16 + rlh * 8 + jh];
        #pragma unroll
        for (int e = 0; e < 8; ++e) wsv[e] += pv * fv[jh][e];
    }
    #pragma unroll
    for (int e = 0; e < 8; ++e) atomicAdd(&acc2[colb + e], wsv[e]);
    __syncthreads();
    if (t < 128) atomicAdd(&accum[t], acc2[t]);
    if (t < 64) {
        float v = pl[t] + pl[t + 64];
        #pragma unroll
        for (int o = 32; o > 0; o >>= 1) v += __shfl_xor(v, o);
        if (t == 0) atomicAdd(den, v);
    }
}

__global__ void finalize_kernel(const float* __restrict__ accum, const float* __restrict__ den,
                                float* __restrict__ out) {
    out[threadIdx.x] = accum[threadIdx.x] / den[0];
}

// ---------------------------------------------------------------- launch
extern "C" void kernel_launch(void* const* d_in, const int* in_sizes, int n_in,
                              void* d_out, int out_size, void* d_ws, size_t ws_size,
                              hipStream_t stream) {
    const int*   node_ids    = (const int*)d_in[0];
    const int*   edges       = (const int*)d_in[1];
    const int*   edge_types  = (const int*)d_in[2];
    const float* embed_table = (const float*)d_in[3];
    const float* edge_tab    = (const float*)d_in[4];
    const float* ggnn_w      = (const float*)d_in[5];
    const float* Wih         = (const float*)d_in[6];
    const float* Whh         = (const float*)d_in[7];
    const float* bih         = (const float*)d_in[8];
    const float* bhh         = (const float*)d_in[9];
    const float* gate_w      = (const float*)d_in[10];
    const float* gate_b      = (const float*)d_in[11];
    float* out = (float*)d_out;

    const size_t PL = (size_t)NPAD * DD;       // plane elems
    ush_t* wsb  = (ush_t*)d_ws;
    ush_t* xH   = wsb;             ush_t* xL   = xH + PL;
    ush_t* x2H  = xL + PL;         ush_t* x2L  = x2H + PL;
    ush_t* agH  = x2L + PL;        ush_t* agL  = agH + PL;
    ush_t* mRM  = agL + PL;        // single plane, row-major
    ush_t* WB   = mRM + PL;        // 10*4*2*4096
    float* csr_w = (float*)(WB + 10 * 4 * 2 * 4096);
    float* accum = csr_w + NE;     // 128
    float* den   = accum + DD;     // 1
    float* rm    = den + 1;        // 7(+1)
    int*   rp    = (int*)(rm + 8); // N+1
    int*   fill  = rp + NN + 1;    // N
    int*   csr_s = fill + NN;      // E
    int*   bsum  = csr_s + NE;     // 128
    int*   boff  = bsum + 128;     // 128

    const int* src = edges;
    const int* dst = edges + NE;

    // one-time prep
    rowmean_kernel<<<7, 128, 0, stream>>>(edge_tab, rm);
    hipMemsetAsync(fill, 0, NN * sizeof(int), stream);
    hist_kernel<<<(NE + 255) / 256, 256, 0, stream>>>(dst, fill);
    scanA_kernel<<<SCANB, 1024, 0, stream>>>(fill, rp, bsum);
    scanB_kernel<<<1, 128, 0, stream>>>(bsum, boff);
    scanC_kernel<<<(NN + 255) / 256, 256, 0, stream>>>(rp, boff);
    hipMemsetAsync(fill, 0, NN * sizeof(int), stream);
    place_kernel<<<(NE + 255) / 256, 256, 0, stream>>>(src, dst, edge_types, rm, rp, fill,
                                                       csr_s, csr_w);
    embed_kernel<<<NPAD * 16 / 256, 256, 0, stream>>>(node_ids, embed_table, xH, xL);
    wprep_kernel<<<640, 256, 0, stream>>>(Wih, Whh, ggnn_w, WB);

    // 4 GGNN layers
    for (int layer = 0; layer < 4; ++layer) {
        gemm_mfma_kernel<<<NT2, 256, 0, stream>>>(xH, xL, WB, 6 + layer, mRM);
        agg_kernel<<<(NPAD + 15) / 16, 512, 0, stream>>>(mRM, rp, csr_s, csr_w, agH, agL);
        gru_mfma_kernel<<<NT2, 256, 0, stream>>>(agH, agL, xH, xL, WB, bih, bhh, x2H, x2L);
        ush_t* th = xH; xH = x2H; x2H = th;
        ush_t* tl = xL; xL = x2L; x2L = tl;
    }

    // global attention pooling
    hipMemsetAsync(accum, 0, (DD + 1) * sizeof(float), stream);
    pool_kernel<<<NT, 256, 0, stream>>>(xH, xL, gate_w, gate_b, accum, den);
    finalize_kernel<<<1, 128, 0, stream>>>(accum, den, out);
}

// Round 9
// 928.928 us; speedup vs baseline: 1.7818x; 1.0821x over previous
//
#include <hip/hip_runtime.h>
#include <math.h>

#define NN 100000
#define NPAD 100096
#define NT 782        // NPAD / 128  (memory tiles)
#define NT2 1564      // NPAD / 64   (gemm/gru blocks)
#define NE 800000
#define DD 128
#define SCANB 98      // ceil(NN/1024)

typedef __attribute__((ext_vector_type(8))) short short8;
typedef __attribute__((ext_vector_type(4))) float floatx4;
typedef unsigned short ush_t;
typedef __attribute__((ext_vector_type(8))) unsigned short ushort8_t;

__device__ __forceinline__ ush_t f2bf(float f) {
    unsigned u = __float_as_uint(f);
    return (ush_t)((u + 0x7fffu + ((u >> 16) & 1u)) >> 16);
}
__device__ __forceinline__ float bf2f(ush_t h) {
    return __uint_as_float((unsigned)h << 16);
}
__device__ __forceinline__ void split2(float f, ush_t* H, ush_t* L) {
    ush_t h = f2bf(f);
    *H = h;
    *L = f2bf(f - bf2f(h));
}
__device__ __forceinline__ float sigf(float x) {
    return __builtin_amdgcn_rcpf(1.0f + __expf(-x));
}
__device__ __forceinline__ float tanhf_fast(float x) {
    x = fminf(fmaxf(x, -20.0f), 20.0f);
    float e = __expf(2.0f * x);
    return 1.0f - 2.0f * __builtin_amdgcn_rcpf(e + 1.0f);
}

// ---------------------------------------------------------------- row means of edge-type table
__global__ void rowmean_kernel(const float* __restrict__ tab, float* __restrict__ rm) {
    int r = blockIdx.x;
    int t = threadIdx.x;
    float v = tab[r * DD + t];
    #pragma unroll
    for (int o = 32; o > 0; o >>= 1) v += __shfl_xor(v, o);
    __shared__ float red[2];
    if ((t & 63) == 0) red[t >> 6] = v;
    __syncthreads();
    if (t == 0) rm[r] = (red[0] + red[1]) * (1.0f / DD);
}

// ---------------------------------------------------------------- CSR build
__global__ void hist_kernel(const int* __restrict__ dst, int* __restrict__ fill) {
    int e = blockIdx.x * 256 + threadIdx.x;
    if (e < NE) atomicAdd(&fill[dst[e]], 1);
}

__global__ __launch_bounds__(1024) void scanA_kernel(const int* __restrict__ cnt,
                                                     int* __restrict__ rp,
                                                     int* __restrict__ bsum) {
    __shared__ int wsum[16];
    int t = threadIdx.x;
    int i = blockIdx.x * 1024 + t;
    int lane = t & 63, w = t >> 6;
    int v = (i < NN) ? cnt[i] : 0;
    int sv = v;
    #pragma unroll
    for (int off = 1; off < 64; off <<= 1) {
        int u = __shfl_up(sv, off);
        if (lane >= off) sv += u;
    }
    if (lane == 63) wsum[w] = sv;
    __syncthreads();
    int woff = 0;
    #pragma unroll
    for (int j = 0; j < 16; ++j) woff += (j < w) ? wsum[j] : 0;
    if (i < NN) rp[i + 1] = sv + woff;
    if (t == 1023) bsum[blockIdx.x] = sv + woff;
}

__global__ __launch_bounds__(128) void scanB_kernel(const int* __restrict__ bsum,
                                                    int* __restrict__ boff) {
    __shared__ int wsum[2];
    int t = threadIdx.x;
    int lane = t & 63, w = t >> 6;
    int v = (t < SCANB) ? bsum[t] : 0;
    int sv = v;
    #pragma unroll
    for (int off = 1; off < 64; off <<= 1) {
        int u = __shfl_up(sv, off);
        if (lane >= off) sv += u;
    }
    if (lane == 63) wsum[w] = sv;
    __syncthreads();
    int woff = (w == 1) ? wsum[0] : 0;
    if (t < SCANB) boff[t] = sv + woff - v;   // exclusive
}

__global__ __launch_bounds__(256) void scanC_kernel(int* __restrict__ rp,
                                                    const int* __restrict__ boff) {
    int i = blockIdx.x * 256 + threadIdx.x;
    if (i == 0) rp[0] = 0;
    if (i < NN) rp[i + 1] += boff[i >> 10];
}

__global__ void place_kernel(const int* __restrict__ src, const int* __restrict__ dst,
                             const int* __restrict__ et, const float* __restrict__ rm,
                             const int* __restrict__ rp, int* __restrict__ fill,
                             int* __restrict__ csr_s, float* __restrict__ csr_w) {
    int e = blockIdx.x * 256 + threadIdx.x;
    if (e < NE) {
        int d = dst[e];
        int pos = rp[d] + atomicAdd(&fill[d], 1);
        csr_s[pos] = src[e];
        csr_w[pos] = rm[et[e] - 1];
    }
}

// ---------------------------------------------------------------- embedding gather → H/L planes
__global__ void embed_kernel(const int* __restrict__ ids, const float* __restrict__ tab,
                             ush_t* __restrict__ xH, ush_t* __restrict__ xL) {
    int tid = blockIdx.x * 256 + threadIdx.x;   // NPAD*16
    int n = tid >> 4, c = tid & 15;
    if (n >= NPAD) return;
    int k = c * 8;
    int base = ((n >> 7) << 14) + ((k >> 5) << 12) + (((n >> 4) & 7) << 9)
             + (((k >> 3) & 3) << 7) + ((n & 15) << 3);
    ushort4 h0, h1, l0, l1;
    if (n < NN) {
        const float4* srcp = (const float4*)(tab + (size_t)(ids[n] + 1) * DD + k);
        float4 v0 = srcp[0], v1 = srcp[1];
        split2(v0.x, &h0.x, &l0.x); split2(v0.y, &h0.y, &l0.y);
        split2(v0.z, &h0.z, &l0.z); split2(v0.w, &h0.w, &l0.w);
        split2(v1.x, &h1.x, &l1.x); split2(v1.y, &h1.y, &l1.y);
        split2(v1.z, &h1.z, &l1.z); split2(v1.w, &h1.w, &l1.w);
    } else {
        h0 = make_ushort4(0, 0, 0, 0); h1 = h0; l0 = h0; l1 = h0;
    }
    *(ushort4*)(xH + base) = h0; *(ushort4*)(xH + base + 4) = h1;
    *(ushort4*)(xL + base) = l0; *(ushort4*)(xL + base + 4) = l1;
}

// ---------------------------------------------------------------- weight prep
// mats 0..2: Whh gates r,z,n | 3..5: Wih gates r,z,n | 6..9: ggnn layer W
__global__ void wprep_kernel(const float* __restrict__ Wih, const float* __restrict__ Whh,
                             const float* __restrict__ G, ush_t* __restrict__ WB) {
    int idx = blockIdx.x * 256 + threadIdx.x;   // 10*16384
    int mat = idx >> 14;
    int rem = idx & 16383;
    int col = rem & 127, kk = rem >> 7;
    float w;
    if (mat < 3)      w = Whh[((size_t)mat * 128 + col) * 128 + kk];
    else if (mat < 6) w = Wih[((size_t)(mat - 3) * 128 + col) * 128 + kk];
    else              w = G[(size_t)(mat - 6) * 16384 + (size_t)kk * 128 + col];
    int chunk = kk >> 5, klo = kk & 31;
    int inoff = ((col >> 4) * 4 + (klo >> 3)) * 128 + (col & 15) * 8 + (klo & 7);
    ush_t h, l;
    split2(w, &h, &l);
    size_t base = (size_t)((mat * 4 + chunk) * 2) * 4096;
    WB[base + inoff] = h;
    WB[base + 4096 + inoff] = l;
}

// ---------------------------------------------------------------- m = x @ W  (layer 0 only)
__global__ __launch_bounds__(256, 4) void gemm_mfma_kernel(const ush_t* __restrict__ xH,
                                                           const ush_t* __restrict__ xL,
                                                           const ush_t* __restrict__ WB,
                                                           int mat, ush_t* __restrict__ mRM) {
    __shared__ float sM[64 * 132];
    int t = threadIdx.x;
    int tb = blockIdx.x;                 // 64-row tile
    int l = t & 63, w = t >> 6;          // w = colgrp 0..3
    int lg = l >> 4, lc = l & 15;
    floatx4 acc[4][2];
    #pragma unroll
    for (int i = 0; i < 4; ++i)
        #pragma unroll
        for (int j = 0; j < 2; ++j) acc[i][j] = (floatx4)0.f;
    int abase = (tb >> 1) * 16384 + (tb & 1) * 2048 + lg * 128 + lc * 8;
    #pragma unroll
    for (int kc = 0; kc < 4; ++kc) {
        short8 aH[4], aL[4];
        #pragma unroll
        for (int i = 0; i < 4; ++i) {
            int off = abase + kc * 4096 + i * 512;
            aH[i] = *(const short8*)(xH + off);
            aL[i] = *(const short8*)(xL + off);
        }
        #pragma unroll
        for (int j = 0; j < 2; ++j) {
            int boff = (((w * 2 + j) * 4 + lg) * 16 + lc) * 8;
            const ush_t* wb = WB + (size_t)((mat * 4 + kc) * 2) * 4096;
            short8 bH = *(const short8*)(wb + boff);
            short8 bL = *(const short8*)(wb + 4096 + boff);
            #pragma unroll
            for (int i = 0; i < 4; ++i) {
                acc[i][j] = __builtin_amdgcn_mfma_f32_16x16x32_bf16(aH[i], bH, acc[i][j], 0, 0, 0);
                acc[i][j] = __builtin_amdgcn_mfma_f32_16x16x32_bf16(aH[i], bL, acc[i][j], 0, 0, 0);
                acc[i][j] = __builtin_amdgcn_mfma_f32_16x16x32_bf16(aL[i], bH, acc[i][j], 0, 0, 0);
            }
        }
    }
    #pragma unroll
    for (int j = 0; j < 2; ++j)
        #pragma unroll
        for (int i = 0; i < 4; ++i)
            #pragma unroll
            for (int r = 0; r < 4; ++r)
                sM[(i * 16 + lg * 4 + r) * 132 + w * 32 + j * 16 + lc] = acc[i][j][r];
    __syncthreads();
    int t4 = t >> 4, tl = t & 15;
    #pragma unroll
    for (int jj = 0; jj < 4; ++jj) {
        const float* srcp = &sM[(jj * 16 + t4) * 132 + tl * 8];
        ushort8_t o;
        #pragma unroll
        for (int e = 0; e < 8; ++e) o[e] = f2bf(srcp[e]);
        *(ushort8_t*)(mRM + (size_t)tb * 8192 + jj * 2048 + t * 8) = o;
    }
}

// ---------------------------------------------------------------- CSR aggregation (unroll x2)
__global__ __launch_bounds__(512) void agg_kernel(const ush_t* __restrict__ m,
                                                  const int* __restrict__ rp,
                                                  const int* __restrict__ csr_s,
                                                  const float* __restrict__ csr_w,
                                                  ush_t* __restrict__ aggH,
                                                  ush_t* __restrict__ aggL) {
    int t = threadIdx.x;
    int grp = t >> 5, c = t & 31;
    int n = blockIdx.x * 16 + grp;
    if (n >= NPAD) return;
    int nout = ((n >> 7) << 14) + ((c >> 3) << 12) + (((n >> 4) & 7) << 9)
             + (((c >> 1) & 3) << 7) + ((n & 15) << 3) + ((c & 1) << 2);
    ushort4 zh = make_ushort4(0, 0, 0, 0);
    if (n >= NN) {
        *(ushort4*)(aggH + nout) = zh;
        *(ushort4*)(aggL + nout) = zh;
        return;
    }
    int e0 = rp[n], e1 = rp[n + 1];
    float4 acc = make_float4(0.f, 0.f, 0.f, 0.f);
    int e = e0;
    for (; e + 1 < e1; e += 2) {
        float w0 = csr_w[e], w1 = csr_w[e + 1];
        int s0 = csr_s[e], s1 = csr_s[e + 1];
        ushort4 p0 = *(const ushort4*)(m + (size_t)s0 * DD + c * 4);
        ushort4 p1 = *(const ushort4*)(m + (size_t)s1 * DD + c * 4);
        acc.x += w0 * bf2f(p0.x) + w1 * bf2f(p1.x);
        acc.y += w0 * bf2f(p0.y) + w1 * bf2f(p1.y);
        acc.z += w0 * bf2f(p0.z) + w1 * bf2f(p1.z);
        acc.w += w0 * bf2f(p0.w) + w1 * bf2f(p1.w);
    }
    if (e < e1) {
        float w0 = csr_w[e];
        int s0 = csr_s[e];
        ushort4 p0 = *(const ushort4*)(m + (size_t)s0 * DD + c * 4);
        acc.x += w0 * bf2f(p0.x);
        acc.y += w0 * bf2f(p0.y);
        acc.z += w0 * bf2f(p0.z);
        acc.w += w0 * bf2f(p0.w);
    }
    ushort4 oh, ol;
    split2(acc.x, &oh.x, &ol.x); split2(acc.y, &oh.y, &ol.y);
    split2(acc.z, &oh.z, &ol.z); split2(acc.w, &oh.w, &ol.w);
    *(ushort4*)(aggH + nout) = oh;
    *(ushort4*)(aggL + nout) = ol;
}

// ---------------------------------------------------------------- fused GRU + next-layer GEMM
// pass 0: A = x vs Whh (mats 0..2) → accR,accZ,accN ; pass 1: A = agg vs Wih (3..5) → accR,accZ,accI
// then x_new tile (in LDS) -> m_next = x_new @ W[next_mat] (bf16-H A, H/L B), if next_mat >= 0
__global__ __launch_bounds__(256, 2) void gru_mfma_kernel(const ush_t* __restrict__ aggH,
                                                          const ush_t* __restrict__ aggL,
                                                          const ush_t* __restrict__ xH,
                                                          const ush_t* __restrict__ xL,
                                                          const ush_t* __restrict__ WB,
                                                          const float* __restrict__ bih,
                                                          const float* __restrict__ bhh,
                                                          ush_t* __restrict__ xoH,
                                                          ush_t* __restrict__ xoL,
                                                          int next_mat,
                                                          ush_t* __restrict__ mOut) {
    __shared__ float sV[64 * 132];
    int t = threadIdx.x;
    int tb = blockIdx.x;                 // 64-row tile
    int l = t & 63, w = t >> 6;          // w = colgrp
    int lg = l >> 4, lc = l & 15;
    floatx4 accR[4][2], accZ[4][2], accN[4][2], accI[4][2];
    #pragma unroll
    for (int i = 0; i < 4; ++i)
        #pragma unroll
        for (int j = 0; j < 2; ++j) {
            accR[i][j] = (floatx4)0.f; accZ[i][j] = (floatx4)0.f;
            accN[i][j] = (floatx4)0.f; accI[i][j] = (floatx4)0.f;
        }
    int abase = (tb >> 1) * 16384 + (tb & 1) * 2048 + lg * 128 + lc * 8;
    #pragma unroll
    for (int pass = 0; pass < 2; ++pass) {
        const ush_t* ApH = pass ? aggH : xH;
        const ush_t* ApL = pass ? aggL : xL;
        int matbase = pass ? 3 : 0;
        #pragma unroll
        for (int kc = 0; kc < 4; ++kc) {
            short8 aHf[4], aLf[4];
            #pragma unroll
            for (int i = 0; i < 4; ++i) {
                int off = abase + kc * 4096 + i * 512;
                aHf[i] = *(const short8*)(ApH + off);
                aLf[i] = *(const short8*)(ApL + off);
            }
            #pragma unroll
            for (int m3 = 0; m3 < 3; ++m3) {
                floatx4 (*accp)[2] = (m3 == 0) ? accR : (m3 == 1) ? accZ : (pass ? accI : accN);
                const ush_t* wb = WB + (size_t)(((matbase + m3) * 4 + kc) * 2) * 4096;
                #pragma unroll
                for (int j = 0; j < 2; ++j) {
                    int boff = (((w * 2 + j) * 4 + lg) * 16 + lc) * 8;
                    short8 bH = *(const short8*)(wb + boff);
                    short8 bL = *(const short8*)(wb + 4096 + boff);
                    #pragma unroll
                    for (int i = 0; i < 4; ++i) {
                        accp[i][j] = __builtin_amdgcn_mfma_f32_16x16x32_bf16(aHf[i], bH, accp[i][j], 0, 0, 0);
                        accp[i][j] = __builtin_amdgcn_mfma_f32_16x16x32_bf16(aHf[i], bL, accp[i][j], 0, 0, 0);
                        accp[i][j] = __builtin_amdgcn_mfma_f32_16x16x32_bf16(aLf[i], bH, accp[i][j], 0, 0, 0);
                    }
                }
            }
        }
    }
    // gates + blend → LDS (h reload is L1/L2-hot — just streamed by pass-0 A-loads)
    #pragma unroll
    for (int j = 0; j < 2; ++j) {
        int col = w * 32 + j * 16 + lc;
        float bIr = bih[col],       bHr = bhh[col];
        float bIz = bih[128 + col], bHz = bhh[128 + col];
        float bIn = bih[256 + col], bHn = bhh[256 + col];
        int cpart = w * 4096 + (j * 2 + (lc >> 3)) * 128 + (lc & 7);
        #pragma unroll
        for (int i = 0; i < 4; ++i)
            #pragma unroll
            for (int r = 0; r < 4; ++r) {
                int row = tb * 64 + i * 16 + lg * 4 + r;
                float v = 0.f;
                if (row < NN) {
                    int idx = (tb >> 1) * 16384 + ((tb & 1) * 4 + i) * 512
                            + (lg * 4 + r) * 8 + cpart;
                    float rr = sigf(accR[i][j][r] + bIr + bHr);
                    float zz = sigf(accZ[i][j][r] + bIz + bHz);
                    float nn = tanhf_fast(accI[i][j][r] + bIn + rr * (accN[i][j][r] + bHn));
                    float h = bf2f(xH[idx]) + bf2f(xL[idx]);
                    v = (1.0f - zz) * nn + zz * h;
                }
                sV[(i * 16 + lg * 4 + r) * 132 + col] = v;
            }
    }
    __syncthreads();
    // linear coalesced write-out of x_new planes
    int t4 = t >> 4, tl = t & 15;
    #pragma unroll
    for (int jj = 0; jj < 4; ++jj) {
        const float* srcp = &sV[(jj * 16 + t4) * 132 + tl * 8];
        ushort8_t oh, ol;
        #pragma unroll
        for (int e = 0; e < 8; ++e) {
            ush_t H, L;
            split2(srcp[e], &H, &L);
            oh[e] = H; ol[e] = L;
        }
        int oidx = (tb >> 1) * 16384 + (tl >> 2) * 4096 + ((tb & 1) * 4 + jj) * 512
                 + (tl & 3) * 128 + t4 * 8;
        *(ushort8_t*)(xoH + oidx) = oh;
        *(ushort8_t*)(xoL + oidx) = ol;
    }
    // ---- fused next-layer GEMM: m_next = x_new @ W[next_mat]
    if (next_mat >= 0) {
        floatx4 mc[4][2];
        #pragma unroll
        for (int i = 0; i < 4; ++i)
            #pragma unroll
            for (int j = 0; j < 2; ++j) mc[i][j] = (floatx4)0.f;
        #pragma unroll
        for (int kc = 0; kc < 4; ++kc) {
            short8 aH[4];
            #pragma unroll
            for (int i = 0; i < 4; ++i) {
                const float* sp = &sV[(i * 16 + lc) * 132 + kc * 32 + lg * 8];
                short8 a;
                #pragma unroll
                for (int e = 0; e < 8; ++e) a[e] = (short)f2bf(sp[e]);
                aH[i] = a;
            }
            const ush_t* wb = WB + (size_t)((next_mat * 4 + kc) * 2) * 4096;
            #pragma unroll
            for (int j = 0; j < 2; ++j) {
                int boff = (((w * 2 + j) * 4 + lg) * 16 + lc) * 8;
                short8 bH = *(const short8*)(wb + boff);
                short8 bL = *(const short8*)(wb + 4096 + boff);
                #pragma unroll
                for (int i = 0; i < 4; ++i) {
                    mc[i][j] = __builtin_amdgcn_mfma_f32_16x16x32_bf16(aH[i], bH, mc[i][j], 0, 0, 0);
                    mc[i][j] = __builtin_amdgcn_mfma_f32_16x16x32_bf16(aH[i], bL, mc[i][j], 0, 0, 0);
                }
            }
        }
        __syncthreads();   // done reading x_new from sV
        #pragma unroll
        for (int j = 0; j < 2; ++j)
            #pragma unroll
            for (int i = 0; i < 4; ++i)
                #pragma unroll
                for (int r = 0; r < 4; ++r)
                    sV[(i * 16 + lg * 4 + r) * 132 + w * 32 + j * 16 + lc] = mc[i][j][r];
        __syncthreads();
        #pragma unroll
        for (int jj = 0; jj < 4; ++jj) {
            const float* srcp = &sV[(jj * 16 + t4) * 132 + tl * 8];
            ushort8_t o;
            #pragma unroll
            for (int e = 0; e < 8; ++e) o[e] = f2bf(srcp[e]);
            *(ushort8_t*)(mOut + (size_t)tb * 8192 + jj * 2048 + t * 8) = o;
        }
    }
}

// ---------------------------------------------------------------- fused pooling (tile-based, planes)
__global__ __launch_bounds__(256) void pool_kernel(const ush_t* __restrict__ xH,
                                                   const ush_t* __restrict__ xL,
                                                   const float* __restrict__ gw,
                                                   const float* __restrict__ gb,
                                                   float* __restrict__ accum,
                                                   float* __restrict__ den) {
    __shared__ float sgw[128];
    __shared__ float rowsum[128];
    __shared__ float pl[128];
    __shared__ float acc2[128];
    int t = threadIdx.x;
    int tb = blockIdx.x;                 // 128-row memory tile
    if (t < 128) { sgw[t] = gw[t]; rowsum[t] = 0.f; acc2[t] = 0.f; }
    __syncthreads();
    const ush_t* xh = xH + (size_t)tb * 16384;
    const ush_t* xl = xL + (size_t)tb * 16384;
    int kc = t >> 6, rg = (t >> 3) & 7, cb = (t >> 1) & 3, rlh = t & 1;
    int colb = kc * 32 + cb * 8;
    float fv[8][8];
    float g[8];
    #pragma unroll
    for (int e = 0; e < 8; ++e) g[e] = sgw[colb + e];
    #pragma unroll
    for (int jh = 0; jh < 8; ++jh) {
        int base = t * 64 + jh * 8;
        short8 a = *(const short8*)(xh + base);
        short8 b = *(const short8*)(xl + base);
        float s = 0.f;
        #pragma unroll
        for (int e = 0; e < 8; ++e) {
            float f = bf2f((ush_t)a[e]) + bf2f((ush_t)b[e]);
            fv[jh][e] = f;
            s += f * g[e];
        }
        atomicAdd(&rowsum[rg * 16 + rlh * 8 + jh], s);
    }
    __syncthreads();
    if (t < 128) {
        int row = tb * 128 + t;
        float pv = 0.f;
        if (row < NN) pv = __expf(sigf(rowsum[t] + gb[0]));
        pl[t] = pv;
    }
    __syncthreads();
    float wsv[8];
    #pragma unroll
    for (int e = 0; e < 8; ++e) wsv[e] = 0.f;
    #pragma unroll
    for (int jh = 0; jh < 8; ++jh) {
        float pv = pl[rg * 16 + rlh * 8 + jh];
        #pragma unroll
        for (int e = 0; e < 8; ++e) wsv[e] += pv * fv[jh][e];
    }
    #pragma unroll
    for (int e = 0; e < 8; ++e) atomicAdd(&acc2[colb + e], wsv[e]);
    __syncthreads();
    if (t < 128) atomicAdd(&accum[t], acc2[t]);
    if (t < 64) {
        float v = pl[t] + pl[t + 64];
        #pragma unroll
        for (int o = 32; o > 0; o >>= 1) v += __shfl_xor(v, o);
        if (t == 0) atomicAdd(den, v);
    }
}

__global__ void finalize_kernel(const float* __restrict__ accum, const float* __restrict__ den,
                                float* __restrict__ out) {
    out[threadIdx.x] = accum[threadIdx.x] / den[0];
}

// ---------------------------------------------------------------- launch
extern "C" void kernel_launch(void* const* d_in, const int* in_sizes, int n_in,
                              void* d_out, int out_size, void* d_ws, size_t ws_size,
                              hipStream_t stream) {
    const int*   node_ids    = (const int*)d_in[0];
    const int*   edges       = (const int*)d_in[1];
    const int*   edge_types  = (const int*)d_in[2];
    const float* embed_table = (const float*)d_in[3];
    const float* edge_tab    = (const float*)d_in[4];
    const float* ggnn_w      = (const float*)d_in[5];
    const float* Wih         = (const float*)d_in[6];
    const float* Whh         = (const float*)d_in[7];
    const float* bih         = (const float*)d_in[8];
    const float* bhh         = (const float*)d_in[9];
    const float* gate_w      = (const float*)d_in[10];
    const float* gate_b      = (const float*)d_in[11];
    float* out = (float*)d_out;

    const size_t PL = (size_t)NPAD * DD;       // plane elems
    ush_t* wsb  = (ush_t*)d_ws;
    ush_t* xH   = wsb;             ush_t* xL   = xH + PL;
    ush_t* x2H  = xL + PL;         ush_t* x2L  = x2H + PL;
    ush_t* agH  = x2L + PL;        ush_t* agL  = agH + PL;
    ush_t* mRM  = agL + PL;        // single plane, row-major
    ush_t* WB   = mRM + PL;        // 10*4*2*4096
    float* csr_w = (float*)(WB + 10 * 4 * 2 * 4096);
    float* accum = csr_w + NE;     // 128
    float* den   = accum + DD;     // 1
    float* rm    = den + 1;        // 7(+1)
    int*   rp    = (int*)(rm + 8); // N+1
    int*   fill  = rp + NN + 1;    // N
    int*   csr_s = fill + NN;      // E
    int*   bsum  = csr_s + NE;     // 128
    int*   boff  = bsum + 128;     // 128

    const int* src = edges;
    const int* dst = edges + NE;

    // one-time prep
    rowmean_kernel<<<7, 128, 0, stream>>>(edge_tab, rm);
    hipMemsetAsync(fill, 0, NN * sizeof(int), stream);
    hist_kernel<<<(NE + 255) / 256, 256, 0, stream>>>(dst, fill);
    scanA_kernel<<<SCANB, 1024, 0, stream>>>(fill, rp, bsum);
    scanB_kernel<<<1, 128, 0, stream>>>(bsum, boff);
    scanC_kernel<<<(NN + 255) / 256, 256, 0, stream>>>(rp, boff);
    hipMemsetAsync(fill, 0, NN * sizeof(int), stream);
    place_kernel<<<(NE + 255) / 256, 256, 0, stream>>>(src, dst, edge_types, rm, rp, fill,
                                                       csr_s, csr_w);
    embed_kernel<<<NPAD * 16 / 256, 256, 0, stream>>>(node_ids, embed_table, xH, xL);
    wprep_kernel<<<640, 256, 0, stream>>>(Wih, Whh, ggnn_w, WB);

    // layer-0 m, then 4 GGNN layers with gemm fused into gru (layers 1..3's m)
    gemm_mfma_kernel<<<NT2, 256, 0, stream>>>(xH, xL, WB, 6, mRM);
    for (int layer = 0; layer < 4; ++layer) {
        agg_kernel<<<(NPAD + 15) / 16, 512, 0, stream>>>(mRM, rp, csr_s, csr_w, agH, agL);
        int next_mat = (layer < 3) ? (7 + layer) : -1;
        gru_mfma_kernel<<<NT2, 256, 0, stream>>>(agH, agL, xH, xL, WB, bih, bhh,
                                                 x2H, x2L, next_mat, mRM);
        ush_t* th = xH; xH = x2H; x2H = th;
        ush_t* tl = xL; xL = x2L; x2L = tl;
    }

    // global attention pooling
    hipMemsetAsync(accum, 0, (DD + 1) * sizeof(float), stream);
    pool_kernel<<<NT, 256, 0, stream>>>(xH, xL, gate_w, gate_b, accum, den);
    finalize_kernel<<<1, 128, 0, stream>>>(accum, den, out);
}

// Round 10
// 662.643 us; speedup vs baseline: 2.4978x; 1.4019x over previous
//
#include <hip/hip_runtime.h>
#include <math.h>

#define NN 100000
#define NPAD 100096
#define NT2 1564      // NPAD / 64   (gemm/gru blocks)
#define NE 800000
#define DD 128
#define SCANB 98      // ceil(NN/1024)

typedef __attribute__((ext_vector_type(8))) short short8;
typedef __attribute__((ext_vector_type(4))) float floatx4;
typedef unsigned short ush_t;
typedef __attribute__((ext_vector_type(8))) unsigned short ushort8_t;

__device__ __forceinline__ ush_t f2bf(float f) {
    unsigned u = __float_as_uint(f);
    return (ush_t)((u + 0x7fffu + ((u >> 16) & 1u)) >> 16);
}
__device__ __forceinline__ float bf2f(ush_t h) {
    return __uint_as_float((unsigned)h << 16);
}
__device__ __forceinline__ float sigf(float x) {
    return __builtin_amdgcn_rcpf(1.0f + __expf(-x));
}
__device__ __forceinline__ float tanhf_fast(float x) {
    x = fminf(fmaxf(x, -20.0f), 20.0f);
    float e = __expf(2.0f * x);
    return 1.0f - 2.0f * __builtin_amdgcn_rcpf(e + 1.0f);
}

// ---------------------------------------------------------------- row means of edge-type table
__global__ void rowmean_kernel(const float* __restrict__ tab, float* __restrict__ rm) {
    int r = blockIdx.x;
    int t = threadIdx.x;
    float v = tab[r * DD + t];
    #pragma unroll
    for (int o = 32; o > 0; o >>= 1) v += __shfl_xor(v, o);
    __shared__ float red[2];
    if ((t & 63) == 0) red[t >> 6] = v;
    __syncthreads();
    if (t == 0) rm[r] = (red[0] + red[1]) * (1.0f / DD);
}

// ---------------------------------------------------------------- CSR build
__global__ void hist_kernel(const int* __restrict__ dst, int* __restrict__ fill) {
    int e = blockIdx.x * 256 + threadIdx.x;
    if (e < NE) atomicAdd(&fill[dst[e]], 1);
}

__global__ __launch_bounds__(1024) void scanA_kernel(const int* __restrict__ cnt,
                                                     int* __restrict__ rp,
                                                     int* __restrict__ bsum) {
    __shared__ int wsum[16];
    int t = threadIdx.x;
    int i = blockIdx.x * 1024 + t;
    int lane = t & 63, w = t >> 6;
    int v = (i < NN) ? cnt[i] : 0;
    int sv = v;
    #pragma unroll
    for (int off = 1; off < 64; off <<= 1) {
        int u = __shfl_up(sv, off);
        if (lane >= off) sv += u;
    }
    if (lane == 63) wsum[w] = sv;
    __syncthreads();
    int woff = 0;
    #pragma unroll
    for (int j = 0; j < 16; ++j) woff += (j < w) ? wsum[j] : 0;
    if (i < NN) rp[i + 1] = sv + woff;
    if (t == 1023) bsum[blockIdx.x] = sv + woff;
}

__global__ __launch_bounds__(128) void scanB_kernel(const int* __restrict__ bsum,
                                                    int* __restrict__ boff) {
    __shared__ int wsum[2];
    int t = threadIdx.x;
    int lane = t & 63, w = t >> 6;
    int v = (t < SCANB) ? bsum[t] : 0;
    int sv = v;
    #pragma unroll
    for (int off = 1; off < 64; off <<= 1) {
        int u = __shfl_up(sv, off);
        if (lane >= off) sv += u;
    }
    if (lane == 63) wsum[w] = sv;
    __syncthreads();
    int woff = (w == 1) ? wsum[0] : 0;
    if (t < SCANB) boff[t] = sv + woff - v;   // exclusive
}

__global__ __launch_bounds__(256) void scanC_kernel(int* __restrict__ rp,
                                                    const int* __restrict__ boff) {
    int i = blockIdx.x * 256 + threadIdx.x;
    if (i == 0) rp[0] = 0;
    if (i < NN) rp[i + 1] += boff[i >> 10];
}

__global__ void place_kernel(const int* __restrict__ src, const int* __restrict__ dst,
                             const int* __restrict__ et, const float* __restrict__ rm,
                             const int* __restrict__ rp, int* __restrict__ fill,
                             int* __restrict__ csr_s, float* __restrict__ csr_w) {
    int e = blockIdx.x * 256 + threadIdx.x;
    if (e < NE) {
        int d = dst[e];
        int pos = rp[d] + atomicAdd(&fill[d], 1);
        csr_s[pos] = src[e];
        csr_w[pos] = rm[et[e] - 1];
    }
}

// ---------------------------------------------------------------- embedding gather → bf16 frag plane
__global__ void embed_kernel(const int* __restrict__ ids, const float* __restrict__ tab,
                             ush_t* __restrict__ xH) {
    int tid = blockIdx.x * 256 + threadIdx.x;   // NPAD*16
    int n = tid >> 4, c = tid & 15;
    if (n >= NPAD) return;
    int k = c * 8;
    int base = ((n >> 7) << 14) + ((k >> 5) << 12) + (((n >> 4) & 7) << 9)
             + (((k >> 3) & 3) << 7) + ((n & 15) << 3);
    ushort8_t h;
    if (n < NN) {
        const float4* srcp = (const float4*)(tab + (size_t)(ids[n] + 1) * DD + k);
        float4 v0 = srcp[0], v1 = srcp[1];
        h[0] = f2bf(v0.x); h[1] = f2bf(v0.y); h[2] = f2bf(v0.z); h[3] = f2bf(v0.w);
        h[4] = f2bf(v1.x); h[5] = f2bf(v1.y); h[6] = f2bf(v1.z); h[7] = f2bf(v1.w);
    } else {
        #pragma unroll
        for (int e = 0; e < 8; ++e) h[e] = 0;
    }
    *(ushort8_t*)(xH + base) = h;
}

// ---------------------------------------------------------------- weight prep (bf16-H only)
// mats 0..2: Whh gates r,z,n | 3..5: Wih gates r,z,n | 6..9: ggnn layer W
__global__ void wprep_kernel(const float* __restrict__ Wih, const float* __restrict__ Whh,
                             const float* __restrict__ G, ush_t* __restrict__ WB) {
    int idx = blockIdx.x * 256 + threadIdx.x;   // 10*16384
    int mat = idx >> 14;
    int rem = idx & 16383;
    int col = rem & 127, kk = rem >> 7;
    float w;
    if (mat < 3)      w = Whh[((size_t)mat * 128 + col) * 128 + kk];
    else if (mat < 6) w = Wih[((size_t)(mat - 3) * 128 + col) * 128 + kk];
    else              w = G[(size_t)(mat - 6) * 16384 + (size_t)kk * 128 + col];
    int chunk = kk >> 5, klo = kk & 31;
    int inoff = ((col >> 4) * 4 + (klo >> 3)) * 128 + (col & 15) * 8 + (klo & 7);
    WB[(size_t)(mat * 4 + chunk) * 4096 + inoff] = f2bf(w);
}

// ---------------------------------------------------------------- m = x @ W  (layer 0 only)
__global__ __launch_bounds__(256, 4) void gemm_mfma_kernel(const ush_t* __restrict__ xH,
                                                           const ush_t* __restrict__ WB,
                                                           int mat, ush_t* __restrict__ mRM) {
    __shared__ float sM[64 * 132];
    int t = threadIdx.x;
    int tb = blockIdx.x;                 // 64-row tile
    int l = t & 63, w = t >> 6;          // w = colgrp 0..3
    int lg = l >> 4, lc = l & 15;
    floatx4 acc[4][2];
    #pragma unroll
    for (int i = 0; i < 4; ++i)
        #pragma unroll
        for (int j = 0; j < 2; ++j) acc[i][j] = (floatx4)0.f;
    int abase = (tb >> 1) * 16384 + (tb & 1) * 2048 + lg * 128 + lc * 8;
    #pragma unroll
    for (int kc = 0; kc < 4; ++kc) {
        short8 aH[4];
        #pragma unroll
        for (int i = 0; i < 4; ++i)
            aH[i] = *(const short8*)(xH + abase + kc * 4096 + i * 512);
        const ush_t* wb = WB + (size_t)(mat * 4 + kc) * 4096;
        #pragma unroll
        for (int j = 0; j < 2; ++j) {
            int boff = (((w * 2 + j) * 4 + lg) * 16 + lc) * 8;
            short8 bH = *(const short8*)(wb + boff);
            #pragma unroll
            for (int i = 0; i < 4; ++i)
                acc[i][j] = __builtin_amdgcn_mfma_f32_16x16x32_bf16(aH[i], bH, acc[i][j], 0, 0, 0);
        }
    }
    #pragma unroll
    for (int j = 0; j < 2; ++j)
        #pragma unroll
        for (int i = 0; i < 4; ++i)
            #pragma unroll
            for (int r = 0; r < 4; ++r)
                sM[(i * 16 + lg * 4 + r) * 132 + w * 32 + j * 16 + lc] = acc[i][j][r];
    __syncthreads();
    int t4 = t >> 4, tl = t & 15;
    #pragma unroll
    for (int jj = 0; jj < 4; ++jj) {
        const float* srcp = &sM[(jj * 16 + t4) * 132 + tl * 8];
        ushort8_t o;
        #pragma unroll
        for (int e = 0; e < 8; ++e) o[e] = f2bf(srcp[e]);
        *(ushort8_t*)(mRM + (size_t)tb * 8192 + jj * 2048 + t * 8) = o;
    }
}

// ---------------------------------------------------------------- CSR aggregation (bf16 in/out)
__global__ __launch_bounds__(512) void agg_kernel(const ush_t* __restrict__ m,
                                                  const int* __restrict__ rp,
                                                  const int* __restrict__ csr_s,
                                                  const float* __restrict__ csr_w,
                                                  ush_t* __restrict__ aggH) {
    int t = threadIdx.x;
    int grp = t >> 5, c = t & 31;
    int n = blockIdx.x * 16 + grp;
    if (n >= NPAD) return;
    int nout = ((n >> 7) << 14) + ((c >> 3) << 12) + (((n >> 4) & 7) << 9)
             + (((c >> 1) & 3) << 7) + ((n & 15) << 3) + ((c & 1) << 2);
    if (n >= NN) {
        *(ushort4*)(aggH + nout) = make_ushort4(0, 0, 0, 0);
        return;
    }
    int e0 = rp[n], e1 = rp[n + 1];
    float4 acc = make_float4(0.f, 0.f, 0.f, 0.f);
    int e = e0;
    for (; e + 1 < e1; e += 2) {
        float w0 = csr_w[e], w1 = csr_w[e + 1];
        int s0 = csr_s[e], s1 = csr_s[e + 1];
        ushort4 p0 = *(const ushort4*)(m + (size_t)s0 * DD + c * 4);
        ushort4 p1 = *(const ushort4*)(m + (size_t)s1 * DD + c * 4);
        acc.x += w0 * bf2f(p0.x) + w1 * bf2f(p1.x);
        acc.y += w0 * bf2f(p0.y) + w1 * bf2f(p1.y);
        acc.z += w0 * bf2f(p0.z) + w1 * bf2f(p1.z);
        acc.w += w0 * bf2f(p0.w) + w1 * bf2f(p1.w);
    }
    if (e < e1) {
        float w0 = csr_w[e];
        int s0 = csr_s[e];
        ushort4 p0 = *(const ushort4*)(m + (size_t)s0 * DD + c * 4);
        acc.x += w0 * bf2f(p0.x);
        acc.y += w0 * bf2f(p0.y);
        acc.z += w0 * bf2f(p0.z);
        acc.w += w0 * bf2f(p0.w);
    }
    ushort4 oh;
    oh.x = f2bf(acc.x); oh.y = f2bf(acc.y); oh.z = f2bf(acc.z); oh.w = f2bf(acc.w);
    *(ushort4*)(aggH + nout) = oh;
}

// ---------------------------------------------------------------- fused GRU + next-layer GEMM / final pooling
// pass 0: A = x vs Whh (0..2) → accR,accZ,accN ; pass 1: A = agg vs Wih (3..5) → accR,accZ,accI
// next_mat >= 0 : write x_new plane + m_next = x_new @ W[next_mat]
// next_mat == -1: fused global-attention pooling from the LDS x_new tile (no x write)
__global__ __launch_bounds__(256, 2) void gru_mfma_kernel(const ush_t* __restrict__ aggH,
                                                          const ush_t* __restrict__ xH,
                                                          const ush_t* __restrict__ WB,
                                                          const float* __restrict__ bih,
                                                          const float* __restrict__ bhh,
                                                          ush_t* __restrict__ xoH,
                                                          int next_mat,
                                                          ush_t* __restrict__ mOut,
                                                          const float* __restrict__ gw,
                                                          const float* __restrict__ gb,
                                                          float* __restrict__ accum,
                                                          float* __restrict__ den) {
    __shared__ float sV[64 * 132];
    __shared__ float pl[64];
    __shared__ float sT[128];
    int t = threadIdx.x;
    int tb = blockIdx.x;                 // 64-row tile
    int l = t & 63, w = t >> 6;          // w = colgrp
    int lg = l >> 4, lc = l & 15;
    floatx4 accR[4][2], accZ[4][2], accN[4][2], accI[4][2];
    #pragma unroll
    for (int i = 0; i < 4; ++i)
        #pragma unroll
        for (int j = 0; j < 2; ++j) {
            accR[i][j] = (floatx4)0.f; accZ[i][j] = (floatx4)0.f;
            accN[i][j] = (floatx4)0.f; accI[i][j] = (floatx4)0.f;
        }
    int abase = (tb >> 1) * 16384 + (tb & 1) * 2048 + lg * 128 + lc * 8;
    #pragma unroll
    for (int pass = 0; pass < 2; ++pass) {
        const ush_t* Ap = pass ? aggH : xH;
        int matbase = pass ? 3 : 0;
        #pragma unroll
        for (int kc = 0; kc < 4; ++kc) {
            short8 aHf[4];
            #pragma unroll
            for (int i = 0; i < 4; ++i)
                aHf[i] = *(const short8*)(Ap + abase + kc * 4096 + i * 512);
            #pragma unroll
            for (int m3 = 0; m3 < 3; ++m3) {
                floatx4 (*accp)[2] = (m3 == 0) ? accR : (m3 == 1) ? accZ : (pass ? accI : accN);
                const ush_t* wb = WB + (size_t)((matbase + m3) * 4 + kc) * 4096;
                #pragma unroll
                for (int j = 0; j < 2; ++j) {
                    int boff = (((w * 2 + j) * 4 + lg) * 16 + lc) * 8;
                    short8 bH = *(const short8*)(wb + boff);
                    #pragma unroll
                    for (int i = 0; i < 4; ++i)
                        accp[i][j] = __builtin_amdgcn_mfma_f32_16x16x32_bf16(aHf[i], bH, accp[i][j], 0, 0, 0);
                }
            }
        }
    }
    // gates + blend → LDS (h reload is L1/L2-hot — just streamed by pass-0 A-loads)
    #pragma unroll
    for (int j = 0; j < 2; ++j) {
        int col = w * 32 + j * 16 + lc;
        float bIr = bih[col],       bHr = bhh[col];
        float bIz = bih[128 + col], bHz = bhh[128 + col];
        float bIn = bih[256 + col], bHn = bhh[256 + col];
        int cpart = w * 4096 + (j * 2 + (lc >> 3)) * 128 + (lc & 7);
        #pragma unroll
        for (int i = 0; i < 4; ++i)
            #pragma unroll
            for (int r = 0; r < 4; ++r) {
                int row = tb * 64 + i * 16 + lg * 4 + r;
                float v = 0.f;
                if (row < NN) {
                    int idx = (tb >> 1) * 16384 + ((tb & 1) * 4 + i) * 512
                            + (lg * 4 + r) * 8 + cpart;
                    float rr = sigf(accR[i][j][r] + bIr + bHr);
                    float zz = sigf(accZ[i][j][r] + bIz + bHz);
                    float nn = tanhf_fast(accI[i][j][r] + bIn + rr * (accN[i][j][r] + bHn));
                    float h = bf2f(xH[idx]);
                    v = (1.0f - zz) * nn + zz * h;
                }
                sV[(i * 16 + lg * 4 + r) * 132 + col] = v;
            }
    }
    __syncthreads();
    int t4 = t >> 4, tl = t & 15;
    if (next_mat >= 0) {
        // coalesced x_new plane write
        #pragma unroll
        for (int jj = 0; jj < 4; ++jj) {
            const float* srcp = &sV[(jj * 16 + t4) * 132 + tl * 8];
            ushort8_t oh;
            #pragma unroll
            for (int e = 0; e < 8; ++e) oh[e] = f2bf(srcp[e]);
            int oidx = (tb >> 1) * 16384 + (tl >> 2) * 4096 + ((tb & 1) * 4 + jj) * 512
                     + (tl & 3) * 128 + t4 * 8;
            *(ushort8_t*)(xoH + oidx) = oh;
        }
        // fused next-layer GEMM: m_next = x_new @ W[next_mat]
        floatx4 mc[4][2];
        #pragma unroll
        for (int i = 0; i < 4; ++i)
            #pragma unroll
            for (int j = 0; j < 2; ++j) mc[i][j] = (floatx4)0.f;
        #pragma unroll
        for (int kc = 0; kc < 4; ++kc) {
            short8 aH[4];
            #pragma unroll
            for (int i = 0; i < 4; ++i) {
                const float* sp = &sV[(i * 16 + lc) * 132 + kc * 32 + lg * 8];
                short8 a;
                #pragma unroll
                for (int e = 0; e < 8; ++e) a[e] = (short)f2bf(sp[e]);
                aH[i] = a;
            }
            const ush_t* wb = WB + (size_t)(next_mat * 4 + kc) * 4096;
            #pragma unroll
            for (int j = 0; j < 2; ++j) {
                int boff = (((w * 2 + j) * 4 + lg) * 16 + lc) * 8;
                short8 bH = *(const short8*)(wb + boff);
                #pragma unroll
                for (int i = 0; i < 4; ++i)
                    mc[i][j] = __builtin_amdgcn_mfma_f32_16x16x32_bf16(aH[i], bH, mc[i][j], 0, 0, 0);
            }
        }
        __syncthreads();   // done reading x_new from sV
        #pragma unroll
        for (int j = 0; j < 2; ++j)
            #pragma unroll
            for (int i = 0; i < 4; ++i)
                #pragma unroll
                for (int r = 0; r < 4; ++r)
                    sV[(i * 16 + lg * 4 + r) * 132 + w * 32 + j * 16 + lc] = mc[i][j][r];
        __syncthreads();
        #pragma unroll
        for (int jj = 0; jj < 4; ++jj) {
            const float* srcp = &sV[(jj * 16 + t4) * 132 + tl * 8];
            ushort8_t o;
            #pragma unroll
            for (int e = 0; e < 8; ++e) o[e] = f2bf(srcp[e]);
            *(ushort8_t*)(mOut + (size_t)tb * 8192 + jj * 2048 + t * 8) = o;
        }
    } else {
        // ---- fused global-attention pooling on the fp32 x_new tile in sV
        int row = t >> 2, q = t & 3;
        const float* rowp = &sV[row * 132 + q * 32];
        const float* gwp = gw + q * 32;
        float s = 0.f;
        #pragma unroll
        for (int e = 0; e < 32; ++e) s += rowp[e] * gwp[e];
        s += __shfl_xor(s, 1);
        s += __shfl_xor(s, 2);
        if (q == 0) {
            int grow = tb * 64 + row;
            pl[row] = (grow < NN) ? __expf(sigf(s + gb[0])) : 0.f;
        }
        __syncthreads();
        int c = t & 127, half = t >> 7;
        float acc = 0.f;
        #pragma unroll
        for (int r = 0; r < 32; ++r)
            acc += pl[half * 32 + r] * sV[(half * 32 + r) * 132 + c];
        if (half == 0) sT[c] = acc;
        __syncthreads();
        if (half == 1) atomicAdd(&accum[c], acc + sT[c]);
        if (t < 64) {
            float v = pl[t];
            #pragma unroll
            for (int o = 32; o > 0; o >>= 1) v += __shfl_xor(v, o);
            if (t == 0) atomicAdd(den, v);
        }
    }
}

__global__ void finalize_kernel(const float* __restrict__ accum, const float* __restrict__ den,
                                float* __restrict__ out) {
    out[threadIdx.x] = accum[threadIdx.x] / den[0];
}

// ---------------------------------------------------------------- launch
extern "C" void kernel_launch(void* const* d_in, const int* in_sizes, int n_in,
                              void* d_out, int out_size, void* d_ws, size_t ws_size,
                              hipStream_t stream) {
    const int*   node_ids    = (const int*)d_in[0];
    const int*   edges       = (const int*)d_in[1];
    const int*   edge_types  = (const int*)d_in[2];
    const float* embed_table = (const float*)d_in[3];
    const float* edge_tab    = (const float*)d_in[4];
    const float* ggnn_w      = (const float*)d_in[5];
    const float* Wih         = (const float*)d_in[6];
    const float* Whh         = (const float*)d_in[7];
    const float* bih         = (const float*)d_in[8];
    const float* bhh         = (const float*)d_in[9];
    const float* gate_w      = (const float*)d_in[10];
    const float* gate_b      = (const float*)d_in[11];
    float* out = (float*)d_out;

    const size_t PL = (size_t)NPAD * DD;       // plane elems
    ush_t* wsb  = (ush_t*)d_ws;
    ush_t* xH   = wsb;
    ush_t* x2H  = xH + PL;
    ush_t* agH  = x2H + PL;
    ush_t* mRM  = agH + PL;        // row-major bf16
    ush_t* WB   = mRM + PL;        // 10*4*4096
    float* csr_w = (float*)(WB + 10 * 4 * 4096);
    float* accum = csr_w + NE;     // 128
    float* den   = accum + DD;     // 1
    float* rm    = den + 1;        // 7(+1)
    int*   rp    = (int*)(rm + 8); // N+1
    int*   fill  = rp + NN + 1;    // N
    int*   csr_s = fill + NN;      // E
    int*   bsum  = csr_s + NE;     // 128
    int*   boff  = bsum + 128;     // 128

    const int* src = edges;
    const int* dst = edges + NE;

    // one-time prep
    rowmean_kernel<<<7, 128, 0, stream>>>(edge_tab, rm);
    hipMemsetAsync(fill, 0, NN * sizeof(int), stream);
    hist_kernel<<<(NE + 255) / 256, 256, 0, stream>>>(dst, fill);
    scanA_kernel<<<SCANB, 1024, 0, stream>>>(fill, rp, bsum);
    scanB_kernel<<<1, 128, 0, stream>>>(bsum, boff);
    scanC_kernel<<<(NN + 255) / 256, 256, 0, stream>>>(rp, boff);
    hipMemsetAsync(fill, 0, NN * sizeof(int), stream);
    place_kernel<<<(NE + 255) / 256, 256, 0, stream>>>(src, dst, edge_types, rm, rp, fill,
                                                       csr_s, csr_w);
    embed_kernel<<<NPAD * 16 / 256, 256, 0, stream>>>(node_ids, embed_table, xH);
    wprep_kernel<<<640, 256, 0, stream>>>(Wih, Whh, ggnn_w, WB);
    hipMemsetAsync(accum, 0, (DD + 1) * sizeof(float), stream);

    // layer-0 m, then 4 GGNN layers; gemm fused into gru (layers 1..3), pooling fused into last gru
    gemm_mfma_kernel<<<NT2, 256, 0, stream>>>(xH, WB, 6, mRM);
    for (int layer = 0; layer < 4; ++layer) {
        agg_kernel<<<(NPAD + 15) / 16, 512, 0, stream>>>(mRM, rp, csr_s, csr_w, agH);
        int next_mat = (layer < 3) ? (7 + layer) : -1;
        gru_mfma_kernel<<<NT2, 256, 0, stream>>>(agH, xH, WB, bih, bhh,
                                                 x2H, next_mat, mRM,
                                                 gate_w, gate_b, accum, den);
        ush_t* th = xH; xH = x2H; x2H = th;
    }

    finalize_kernel<<<1, 128, 0, stream>>>(accum, den, out);
}